// Round 4
// baseline (651.840 us; speedup 1.0000x reference)
//
#include <hip/hip_runtime.h>

// LiZAttention: gated delta-rule linear attention + causal softmax attention,
// shared QKV / output projections. B=2, N=2048, D=2048, H=16, KVH=4, HD=128.

typedef unsigned short u16;
typedef short bf16x8 __attribute__((ext_vector_type(8)));
typedef float f32x4 __attribute__((ext_vector_type(4)));

#define DEV static __device__ __forceinline__

DEV f32x4 mfma(bf16x8 a, bf16x8 b, f32x4 c) {
  return __builtin_amdgcn_mfma_f32_16x16x32_bf16(a, b, c, 0, 0, 0);
}
DEV u16 f2b(float f) {
  unsigned int u = __builtin_bit_cast(unsigned int, f);
  u = (u + 0x7FFF + ((u >> 16) & 1)) >> 16;
  return (u16)u;
}
DEV float b2f(u16 b) {
  unsigned int u = ((unsigned int)b) << 16;
  return __builtin_bit_cast(float, u);
}
DEV unsigned packbf(float a, float b) {  // round-half-up bf16 pair
  unsigned ua = __builtin_bit_cast(unsigned, a) + 0x8000u;
  unsigned ub = __builtin_bit_cast(unsigned, b) + 0x8000u;
  return (ua >> 16) | (ub & 0xffff0000u);
}
DEV float logsig(float x) { return fminf(x, 0.f) - log1pf(__expf(-fabsf(x))); }

DEV void gll16(const u16* g, u16* l) {
  __builtin_amdgcn_global_load_lds(
      (const __attribute__((address_space(1))) void*)g,
      (__attribute__((address_space(3))) void*)l, 16, 0, 0);
}

// ---------------- prep0: hs cast + tiled weight transposes ----------------
__global__ __launch_bounds__(256) void k_prep0(const float* __restrict__ hs,
    const float* __restrict__ wq, const float* __restrict__ wk,
    const float* __restrict__ wv, const float* __restrict__ wo,
    u16* __restrict__ hsb, u16* __restrict__ wqkvT, u16* __restrict__ woT) {
  int bid = blockIdx.x;
  int t = threadIdx.x;
  if (bid < 2048) {
    for (int it = 0; it < 4; it++) {
      long i = (long)bid * 4096 + it * 1024 + t * 4;
      const float4 v = *(const float4*)&hs[i];
      u16 o[4] = {f2b(v.x), f2b(v.y), f2b(v.z), f2b(v.w)};
      *(uint2*)&hsb[i] = *(const uint2*)o;
    }
    return;
  }
  bid -= 2048;
  __shared__ u16 T[64][72];
  const float* s; int sLD; long c0; u16* d; int nb, kb;
  if (bid < 1536) {
    int tn = bid >> 5, tk = bid & 31;
    nb = tn * 64; kb = tk * 64; d = wqkvT;
    if (nb < 2048)      { s = wq; sLD = 2048; c0 = nb; }
    else if (nb < 2560) { s = wk; sLD = 512;  c0 = nb - 2048; }
    else                { s = wv; sLD = 512;  c0 = nb - 2560; }
  } else {
    int b2 = bid - 1536;
    int tn = b2 >> 5, tk = b2 & 31;
    nb = tn * 64; kb = tk * 64; d = woT; s = wo; sLD = 2048; c0 = nb;
  }
  int lr = t >> 4, lc = (t & 15) * 4;
  for (int it = 0; it < 4; it++) {
    int r = lr + it * 16;
    float4 v = *(const float4*)&s[(long)(kb + r) * sLD + c0 + lc];
    u16 o[4] = {f2b(v.x), f2b(v.y), f2b(v.z), f2b(v.w)};
    *(uint2*)&T[r][lc] = *(const uint2*)o;
  }
  __syncthreads();
  int nl = t >> 2, kc = (t & 3) * 16;
  u16 pk[16];
  for (int i = 0; i < 16; i++) pk[i] = T[kc + i][nl];
  u16* dp = &d[(long)(nb + nl) * 2048 + kb + kc];
  *(uint4*)dp = *(const uint4*)pk;
  *(uint4*)(dp + 8) = *(const uint4*)(pk + 8);
}

// ---------------- GEMM (m97 structure): C[M][N] = A[M][K] * Bt[N][K]^T --------
template <int OUT_F32>
__global__ __launch_bounds__(256) void k_gemm(const u16* __restrict__ A,
    const u16* __restrict__ Bt, void* __restrict__ Cout, int M, int N, int K) {
  __shared__ u16 As[8192];
  __shared__ u16 Bs[8192];
  int t = threadIdx.x;
  int w = t >> 6, ln = t & 63, l15 = ln & 15, q = ln >> 4;
  long rb = (long)blockIdx.y * 128, cb = (long)blockIdx.x * 128;
  int wm = (w >> 1) * 64, wn = (w & 1) * 64;
  f32x4 acc[4][4] = {};
  int sr = t >> 3, sc = (t & 7) << 3;
  const u16* Ag = &A[(rb + sr) * (long)K + sc];
  const u16* Bg = &Bt[(cb + sr) * (long)K + sc];
  u16* Asl = &As[t * 8];
  u16* Bsl = &Bs[t * 8];
  for (int k0 = 0; k0 < K; k0 += 64) {
    __syncthreads();
    for (int it = 0; it < 4; it++) {
      gll16(Ag + (long)it * 32 * K + k0, Asl + it * 2048);
      gll16(Bg + (long)it * 32 * K + k0, Bsl + it * 2048);
    }
    __syncthreads();
    for (int ks = 0; ks < 2; ks++) {
      bf16x8 af[4], bfr[4];
      for (int mt = 0; mt < 4; mt++)
        af[mt] = *(const bf16x8*)&As[(wm + mt * 16 + l15) * 64 + ks * 32 + q * 8];
      for (int nt = 0; nt < 4; nt++)
        bfr[nt] = *(const bf16x8*)&Bs[(wn + nt * 16 + l15) * 64 + ks * 32 + q * 8];
      for (int mt = 0; mt < 4; mt++)
        for (int nt = 0; nt < 4; nt++)
          acc[mt][nt] = mfma(af[mt], bfr[nt], acc[mt][nt]);
    }
  }
  for (int mt = 0; mt < 4; mt++)
    for (int nt = 0; nt < 4; nt++)
      for (int r = 0; r < 4; r++) {
        long m = rb + wm + mt * 16 + q * 4 + r;
        long n = cb + wn + nt * 16 + l15;
        if (OUT_F32) ((float*)Cout)[m * N + n] = acc[mt][nt][r];
        else ((u16*)Cout)[m * N + n] = f2b(acc[mt][nt][r]);
      }
}

// ---------------- k_act: q softmax + k softmax/beta (+kbT) + vT -------------
// jobs: [0,1024): q softmax; [1024,1280): k -> ksb,kbb,kbT; [1280,1536): vTb.
__global__ __launch_bounds__(256) void k_act(const u16* __restrict__ qkv,
    u16* __restrict__ qsb, u16* __restrict__ ksb, u16* __restrict__ kbb,
    u16* __restrict__ kbT, u16* __restrict__ vTb) {
  __shared__ u16 T[128][72];
  int bid = blockIdx.x, t = threadIdx.x;
  const float L2E = 1.442695041f;
  if (bid < 1024) {
    int h = bid & 15;
    long rb = (long)(bid >> 4) * 64;
    int row = t >> 2, c = (t & 3) * 32;
    const u16* src = &qkv[(rb + row) * 3072 + h * 128 + c];
    float x[32];
    for (int i = 0; i < 4; i++) {
      uint4 v = *(const uint4*)&src[i * 8];
      unsigned vv[4] = {v.x, v.y, v.z, v.w};
      for (int jj = 0; jj < 4; jj++) {
        x[i * 8 + jj * 2] = b2f((u16)(vv[jj] & 0xffff));
        x[i * 8 + jj * 2 + 1] = b2f((u16)(vv[jj] >> 16));
      }
    }
    float mx = x[0];
    for (int i = 1; i < 32; i++) mx = fmaxf(mx, x[i]);
    mx = fmaxf(mx, __shfl_xor(mx, 1));
    mx = fmaxf(mx, __shfl_xor(mx, 2));
    float sm = 0.f;
    for (int i = 0; i < 32; i++) { x[i] = exp2f((x[i] - mx) * L2E); sm += x[i]; }
    sm += __shfl_xor(sm, 1);
    sm += __shfl_xor(sm, 2);
    float inv = 1.f / sm;
    unsigned pk[16];
    for (int i = 0; i < 16; i++) pk[i] = packbf(x[2 * i] * inv, x[2 * i + 1] * inv);
    u16* dst = &qsb[(rb + row) * 2048 + h * 128 + c];
    for (int i = 0; i < 4; i++) *(uint4*)&dst[i * 8] = *(const uint4*)&pk[i * 4];
    return;
  }
  int idx = bid - 1024;
  int isV = idx >= 256;
  if (isV) idx -= 256;
  int kvg = idx & 3;
  long rb = (long)(idx >> 2) * 64;
  int row = t >> 2, c = (t & 3) * 32;
  int b = (int)(rb >> 11);
  int c8 = b * 4 + kvg;
  long nloc = rb & 2047;
  if (!isV) {
    const u16* src = &qkv[(rb + row) * 3072 + 2048 + kvg * 128 + c];
    float x[32];
    for (int i = 0; i < 4; i++) {
      uint4 v = *(const uint4*)&src[i * 8];
      unsigned vv[4] = {v.x, v.y, v.z, v.w};
      for (int jj = 0; jj < 4; jj++) {
        x[i * 8 + jj * 2] = b2f((u16)(vv[jj] & 0xffff));
        x[i * 8 + jj * 2 + 1] = b2f((u16)(vv[jj] >> 16));
      }
    }
    float bt[32];
    for (int i = 0; i < 32; i++) bt[i] = exp2f(logsig(x[i]) * 0.0901684411f);
    float mx = x[0];
    for (int i = 1; i < 32; i++) mx = fmaxf(mx, x[i]);
    mx = fmaxf(mx, __shfl_xor(mx, 1));
    mx = fmaxf(mx, __shfl_xor(mx, 2));
    float sm = 0.f;
    for (int i = 0; i < 32; i++) { x[i] = exp2f((x[i] - mx) * L2E); sm += x[i]; }
    sm += __shfl_xor(sm, 1);
    sm += __shfl_xor(sm, 2);
    float inv = 1.f / sm;
    unsigned pks[16], pkb[16];
    for (int i = 0; i < 16; i++) {
      float s0 = x[2 * i] * inv, s1 = x[2 * i + 1] * inv;
      pks[i] = packbf(s0, s1);
      pkb[i] = packbf(s0 * bt[2 * i], s1 * bt[2 * i + 1]);
    }
    u16* d1 = &ksb[(rb + row) * 512 + kvg * 128 + c];
    u16* d2 = &kbb[(rb + row) * 512 + kvg * 128 + c];
    for (int i = 0; i < 4; i++) {
      *(uint4*)&d1[i * 8] = *(const uint4*)&pks[i * 4];
      *(uint4*)&d2[i * 8] = *(const uint4*)&pkb[i * 4];
    }
    for (int i = 0; i < 16; i++) {
      T[c + 2 * i][row] = (u16)(pkb[i] & 0xffff);
      T[c + 2 * i + 1][row] = (u16)(pkb[i] >> 16);
    }
  } else {
    const u16* src = &qkv[(rb + row) * 3072 + 2560 + kvg * 128 + c];
    for (int i = 0; i < 4; i++) {
      uint4 v = *(const uint4*)&src[i * 8];
      unsigned vv[4] = {v.x, v.y, v.z, v.w};
      for (int jj = 0; jj < 4; jj++) {
        T[c + i * 8 + jj * 2][row] = (u16)(vv[jj] & 0xffff);
        T[c + i * 8 + jj * 2 + 1][row] = (u16)(vv[jj] >> 16);
      }
    }
  }
  __syncthreads();
  int dr = t >> 1, nc = (t & 1) * 32;
  u16* dst = isV ? vTb : kbT;
  u16* dp = &dst[((long)(c8 * 128 + dr)) * 2048 + nloc + nc];
  for (int i = 0; i < 4; i++)
    *(uint4*)&dp[i * 8] = *(const uint4*)&T[dr][nc + i * 8];
}

// ---------------- delta-rule phase 1 ----------------
// Outputs: W_g[t][d], U0_g[t][e], M_g[i][j], NTT_g[i][e] (f32), per chunk.
__global__ __launch_bounds__(256) void k_phase1(const u16* __restrict__ ksb,
    const u16* __restrict__ kbb, const u16* __restrict__ kbT,
    const u16* __restrict__ qkv, u16* __restrict__ W_g, u16* __restrict__ U0_g,
    u16* __restrict__ M_g, float* __restrict__ NTT_g) {
  __shared__ u16 Pm[64][72];
  __shared__ u16 PT[64][72];
  __shared__ u16 slab[4][64][72];
  int cc = blockIdx.x;
  int c8 = cc >> 5, j = cc & 31;
  int b = c8 >> 2, kv = c8 & 3;
  long rb = (long)b * 2048 + j * 64;
  int w = threadIdx.x >> 6, ln = threadIdx.x & 63, l15 = ln & 15, q = ln >> 4;
  {
    f32x4 a4[4] = {};
    int m0 = w * 16;
    for (int ks = 0; ks < 4; ks++) {
      bf16x8 af = *(const bf16x8*)&ksb[(rb + m0 + l15) * 512 + kv * 128 + ks * 32 + q * 8];
      for (int nt = 0; nt < 4; nt++) {
        bf16x8 bfr = *(const bf16x8*)&kbb[(rb + nt * 16 + l15) * 512 + kv * 128 + ks * 32 + q * 8];
        a4[nt] = mfma(af, bfr, a4[nt]);
      }
    }
    for (int nt = 0; nt < 4; nt++)
      for (int r = 0; r < 4; r++) {
        int m = m0 + q * 4 + r, n = nt * 16 + l15;
        u16 h = f2b((m > n) ? -a4[nt][r] : 0.f);
        Pm[m][n] = h; PT[n][m] = h;
      }
  }
  for (int idx = threadIdx.x; idx < 16384; idx += 256) {
    int s = idx >> 12, rem = idx & 4095, t = rem >> 6, c = rem & 63;
    u16 v;
    if (s < 2) v = ksb[(rb + t) * 512 + kv * 128 + s * 64 + c];
    else       v = qkv[(rb + t) * 3072 + 2560 + kv * 128 + (s - 2) * 64 + c];
    slab[s][c][t] = v;
  }
  __syncthreads();
  f32x4 X[4][4];
  for (int mt = 0; mt < 4; mt++)
    for (int nt = 0; nt < 4; nt++)
      for (int r = 0; r < 4; r++)
        X[mt][nt][r] = b2f(slab[w][nt * 16 + l15][mt * 16 + q * 4 + r]);
  for (int f = 0; f < 6; f++) {
    for (int ks = 0; ks < 2; ks++) {
      bf16x8 af[4], bfr[4];
      for (int mt = 0; mt < 4; mt++)
        af[mt] = *(const bf16x8*)&Pm[mt * 16 + l15][ks * 32 + q * 8];
      for (int nt = 0; nt < 4; nt++)
        bfr[nt] = *(const bf16x8*)&slab[w][nt * 16 + l15][ks * 32 + q * 8];
      for (int mt = 0; mt < 4; mt++)
        for (int nt = 0; nt < 4; nt++)
          X[mt][nt] = mfma(af[mt], bfr[nt], X[mt][nt]);
    }
    f32x4 pn[4] = {};
    if (f < 5) {
      int m0 = w * 16;
      for (int ks = 0; ks < 2; ks++) {
        bf16x8 af = *(const bf16x8*)&Pm[m0 + l15][ks * 32 + q * 8];
        for (int nt = 0; nt < 4; nt++) {
          bf16x8 bfr = *(const bf16x8*)&PT[nt * 16 + l15][ks * 32 + q * 8];
          pn[nt] = mfma(af, bfr, pn[nt]);
        }
      }
    }
    __syncthreads();
    for (int mt = 0; mt < 4; mt++)
      for (int nt = 0; nt < 4; nt++)
        for (int r = 0; r < 4; r++)
          slab[w][nt * 16 + l15][mt * 16 + q * 4 + r] = f2b(X[mt][nt][r]);
    if (f < 5) {
      int m0 = w * 16;
      for (int nt = 0; nt < 4; nt++)
        for (int r = 0; r < 4; r++) {
          int m = m0 + q * 4 + r, n = nt * 16 + l15;
          u16 h = f2b(pn[nt][r]);
          Pm[m][n] = h; PT[n][m] = h;
        }
    }
    __syncthreads();
  }
  for (int idx = threadIdx.x; idx < 8192; idx += 256) {
    int t = idx >> 7, d = idx & 127;
    W_g[(long)cc * 8192 + idx] = slab[d >> 6][d & 63][t];
  }
  for (int idx = threadIdx.x; idx < 8192; idx += 256) {
    int t = idx >> 7, e = idx & 127;
    U0_g[(long)cc * 8192 + idx] = slab[2 + (e >> 6)][e & 63][t];
  }
  {
    f32x4 acc[2][8] = {};
    int m0 = w * 32;
    for (int ks = 0; ks < 2; ks++) {
      bf16x8 af[2], bfr[8];
      for (int mt = 0; mt < 2; mt++)
        af[mt] = *(const bf16x8*)&kbT[((long)(c8 * 128 + m0 + mt * 16 + l15)) * 2048 + j * 64 + ks * 32 + q * 8];
      for (int nt = 0; nt < 8; nt++) {
        int n = nt * 16 + l15;
        bfr[nt] = *(const bf16x8*)&slab[n >> 6][n & 63][ks * 32 + q * 8];
      }
      for (int mt = 0; mt < 2; mt++)
        for (int nt = 0; nt < 8; nt++)
          acc[mt][nt] = mfma(af[mt], bfr[nt], acc[mt][nt]);
    }
    for (int mt = 0; mt < 2; mt++)
      for (int nt = 0; nt < 8; nt++)
        for (int r = 0; r < 4; r++) {
          int i_ = m0 + mt * 16 + q * 4 + r, jj = nt * 16 + l15;
          M_g[(long)cc * 16384 + (long)i_ * 128 + jj] =
              f2b(((i_ == jj) ? 1.f : 0.f) - acc[mt][nt][r]);
        }
  }
  {
    // NT^T = Kb^T U0 : A = kbT rows i, B = U0^T rows e (from slab), k = t.
    f32x4 acc[2][8] = {};
    int m0 = w * 32;
    for (int ks = 0; ks < 2; ks++) {
      bf16x8 af[2], bfr[8];
      for (int mt = 0; mt < 2; mt++)
        af[mt] = *(const bf16x8*)&kbT[((long)(c8 * 128 + m0 + mt * 16 + l15)) * 2048 + j * 64 + ks * 32 + q * 8];
      for (int nt = 0; nt < 8; nt++) {
        int e = nt * 16 + l15;
        bfr[nt] = *(const bf16x8*)&slab[2 + (e >> 6)][e & 63][ks * 32 + q * 8];
      }
      for (int mt = 0; mt < 2; mt++)
        for (int nt = 0; nt < 8; nt++)
          acc[mt][nt] = mfma(af[mt], bfr[nt], acc[mt][nt]);
    }
    for (int mt = 0; mt < 2; mt++)
      for (int nt = 0; nt < 8; nt++)
        for (int r = 0; r < 4; r++) {
          int i_ = m0 + mt * 16 + q * 4 + r, e = nt * 16 + l15;
          NTT_g[(long)cc * 16384 + (long)i_ * 128 + e] = acc[mt][nt][r];
        }
  }
}

// ---------------- phase 2: sequential chunk scan, prefetched ----------------
struct P2Buf { bf16x8 W[4]; bf16x8 M[4][2]; f32x4 NT[2]; ushort4 U0; };

__global__ __launch_bounds__(256) void k_phase2(const u16* __restrict__ W_g,
    const u16* __restrict__ U0_g, const u16* __restrict__ M_g,
    const float* __restrict__ NTT_g, u16* __restrict__ St0_g,
    u16* __restrict__ UT_g) {
  __shared__ u16 St[16][136];
  int c8 = blockIdx.x & 7, eb = blockIdx.x >> 3;
  int e0 = eb * 16;
  int w = threadIdx.x >> 6, ln = threadIdx.x & 63, l15 = ln & 15, q = ln >> 4;
  for (int idx = threadIdx.x; idx < 16 * 128; idx += 256)
    St[idx >> 7][idx & 127] = 0;
  __syncthreads();

  auto loadbuf = [&](P2Buf& B, long cc) {
    for (int ks = 0; ks < 4; ks++)
      B.W[ks] = *(const bf16x8*)&W_g[cc * 8192 + (long)(w * 16 + l15) * 128 + ks * 32 + q * 8];
    for (int ks = 0; ks < 4; ks++)
      for (int nt = 0; nt < 2; nt++)
        B.M[ks][nt] = *(const bf16x8*)&M_g[cc * 16384 + (long)(w * 32 + nt * 16 + l15) * 128 + ks * 32 + q * 8];
    for (int nt = 0; nt < 2; nt++)
      B.NT[nt] = *(const f32x4*)&NTT_g[cc * 16384 + (long)(w * 32 + nt * 16 + l15) * 128 + e0 + q * 4];
    B.U0 = *(const ushort4*)&U0_g[cc * 8192 + (long)(w * 16 + l15) * 128 + e0 + q * 4];
  };

  auto step = [&](long cc, P2Buf& cur, P2Buf& nxt, bool pf) {
    if (pf) loadbuf(nxt, cc + 1);
    for (int idx = threadIdx.x; idx < 2048; idx += 256)
      St0_g[cc * 16384 + (long)(e0 + (idx >> 7)) * 128 + (idx & 127)] = St[idx >> 7][idx & 127];
    bf16x8 sf[4];
    for (int ks = 0; ks < 4; ks++)
      sf[ks] = *(const bf16x8*)&St[l15][ks * 32 + q * 8];
    f32x4 acc = {};
    for (int ks = 0; ks < 4; ks++) acc = mfma(sf[ks], cur.W[ks], acc);
    const u16* u0p = (const u16*)&cur.U0;
    for (int r = 0; r < 4; r++)
      UT_g[cc * 8192 + (long)(e0 + q * 4 + r) * 64 + w * 16 + l15] = f2b(b2f(u0p[r]) - acc[r]);
    f32x4 acc2[2] = {cur.NT[0], cur.NT[1]};
    for (int ks = 0; ks < 4; ks++)
      for (int nt = 0; nt < 2; nt++)
        acc2[nt] = mfma(sf[ks], cur.M[ks][nt], acc2[nt]);
    __syncthreads();
    for (int nt = 0; nt < 2; nt++)
      for (int r = 0; r < 4; r++)
        St[q * 4 + r][w * 32 + nt * 16 + l15] = f2b(acc2[nt][r]);
    __syncthreads();
  };

  P2Buf A, B;
  long base = (long)c8 * 32;
  loadbuf(A, base);
  for (int j = 0; j < 32; j += 2) {
    step(base + j, A, B, true);
    step(base + j + 1, B, A, j + 2 < 32);
  }
}

// ---------------- phase 3 ----------------
__global__ __launch_bounds__(256) void k_phase3(const u16* __restrict__ qsb,
    const u16* __restrict__ kbb, const u16* __restrict__ St0_g,
    const u16* __restrict__ UT_g, u16* __restrict__ o_lin) {
  __shared__ u16 Pl[64][72];
  int cc = blockIdx.x >> 2, hh = blockIdx.x & 3;
  int c8 = cc >> 5, j = cc & 31;
  int b = c8 >> 2, kv = c8 & 3, hq = kv * 4 + hh;
  long rb = (long)b * 2048 + j * 64;
  int w = threadIdx.x >> 6, ln = threadIdx.x & 63, l15 = ln & 15, q = ln >> 4;
  int m0 = w * 16;
  f32x4 O[8] = {};
  for (int ks = 0; ks < 4; ks++) {
    bf16x8 af = *(const bf16x8*)&qsb[(rb + m0 + l15) * 2048 + hq * 128 + ks * 32 + q * 8];
    for (int nt = 0; nt < 8; nt++) {
      bf16x8 bfr = *(const bf16x8*)&St0_g[(long)cc * 16384 + (long)(nt * 16 + l15) * 128 + ks * 32 + q * 8];
      O[nt] = mfma(af, bfr, O[nt]);
    }
  }
  {
    f32x4 p4[4] = {};
    for (int ks = 0; ks < 4; ks++) {
      bf16x8 af = *(const bf16x8*)&qsb[(rb + m0 + l15) * 2048 + hq * 128 + ks * 32 + q * 8];
      for (int nt = 0; nt < 4; nt++) {
        bf16x8 bfr = *(const bf16x8*)&kbb[(rb + nt * 16 + l15) * 512 + kv * 128 + ks * 32 + q * 8];
        p4[nt] = mfma(af, bfr, p4[nt]);
      }
    }
    for (int nt = 0; nt < 4; nt++)
      for (int r = 0; r < 4; r++) {
        int m = m0 + q * 4 + r, n = nt * 16 + l15;
        Pl[m][n] = f2b((m >= n) ? p4[nt][r] : 0.f);
      }
  }
  __syncthreads();
  for (int ks = 0; ks < 2; ks++) {
    bf16x8 af = *(const bf16x8*)&Pl[m0 + l15][ks * 32 + q * 8];
    for (int nt = 0; nt < 8; nt++) {
      bf16x8 bfr = *(const bf16x8*)&UT_g[(long)cc * 8192 + (long)(nt * 16 + l15) * 64 + ks * 32 + q * 8];
      O[nt] = mfma(af, bfr, O[nt]);
    }
  }
  for (int nt = 0; nt < 8; nt++)
    for (int r = 0; r < 4; r++) {
      int m = m0 + q * 4 + r, e = nt * 16 + l15;
      o_lin[(rb + m) * 2048 + hq * 128 + e] = f2b(O[nt][r]);
    }
}

// ---------------- flash: 16-row q-tiles, barrier-free jt loop ----------------
// Block = (b, h, pair{pr, 127-pr}); 2048 blocks, 17 kv-tile units each.
// Wave w owns K/V k-slice [w*32, w*32+32) per 128-tile; P wave-private in LDS;
// K fragments register double-buffered; O k-partials reduced once per q-tile.
__global__ __launch_bounds__(256, 2) void k_flash(const u16* __restrict__ qkv,
    const u16* __restrict__ vTb, const u16* __restrict__ o_lin,
    u16* __restrict__ o_comb) {
  __shared__ u16 P[4][16][40];
  __shared__ float Ored[2][128][20];
  __shared__ float psL[4][16];
  int pr = blockIdx.x & 63, h = (blockIdx.x >> 6) & 15, b = blockIdx.x >> 10;
  int kv = h >> 2;
  int w = threadIdx.x >> 6, ln = threadIdx.x & 63, l15 = ln & 15, q = ln >> 4;
  const float sc2 = 0.127517444f;  // (1/sqrt(128)) * log2(e)
  u16 (*Pw)[40] = P[w];
  const u16* kbase = &qkv[2048 + kv * 128];
  const u16* vbase = &vTb[(long)(b * 4 + kv) * 128 * 2048 + w * 32];
  long kvb = (long)b * 2048;
  for (int sel = 0; sel < 2; sel++) {
    int qt = sel ? 127 - pr : pr;
    long qb = kvb + qt * 16;
    int njt = (qt >> 3) + 1;
    bf16x8 bq[4];
    for (int ks = 0; ks < 4; ks++)
      bq[ks] = *(const bf16x8*)&qkv[(qb + l15) * 3072 + h * 128 + ks * 32 + q * 8];
    f32x4 O[8] = {};
    float psum = 0.f;
    bf16x8 akA[2][4], akB[2][4];
    for (int mt = 0; mt < 2; mt++)
      for (int ks = 0; ks < 4; ks++)
        akA[mt][ks] = *(const bf16x8*)&kbase[(kvb + w * 32 + mt * 16 + l15) * 3072 + ks * 32 + q * 8];

    auto body = [&](int jt, bf16x8 (*cur)[4], bf16x8 (*nxt)[4]) {
      if (jt + 1 < njt) {
        long kb = kvb + (jt + 1) * 128;
        for (int mt = 0; mt < 2; mt++)
          for (int ks = 0; ks < 4; ks++)
            nxt[mt][ks] = *(const bf16x8*)&kbase[(kb + w * 32 + mt * 16 + l15) * 3072 + ks * 32 + q * 8];
      }
      bf16x8 bv[8];
      for (int et = 0; et < 8; et++)
        bv[et] = *(const bf16x8*)&vbase[(long)(et * 16 + l15) * 2048 + jt * 128 + q * 8];
      f32x4 st[2] = {};
      for (int ks = 0; ks < 4; ks++)
        for (int mt = 0; mt < 2; mt++)
          st[mt] = mfma(cur[mt][ks], bq[ks], st[mt]);
      bool last = (jt == njt - 1);
      int rg = qt * 16 + l15;
      for (int mt = 0; mt < 2; mt++) {
        for (int r = 0; r < 4; r++) {
          float pv = exp2f(st[mt][r] * sc2);
          int kg = jt * 128 + w * 32 + mt * 16 + q * 4 + r;
          if (last && kg > rg) pv = 0.f;
          st[mt][r] = pv;
          psum += pv;
        }
        unsigned pu[2];
        pu[0] = packbf(st[mt][0], st[mt][1]);
        pu[1] = packbf(st[mt][2], st[mt][3]);
        *(uint2*)&Pw[l15][mt * 16 + q * 4] = *(const uint2*)pu;
      }
      bf16x8 ap = *(const bf16x8*)&Pw[l15][q * 8];
      for (int et = 0; et < 8; et++)
        O[et] = mfma(ap, bv[et], O[et]);
    };
    for (int jt = 0; jt < njt; jt += 2) {
      body(jt, akA, akB);
      if (jt + 1 < njt) body(jt + 1, akB, akA);
    }
    psum += __shfl_xor(psum, 16);
    psum += __shfl_xor(psum, 32);
    if (q == 0) psL[w][l15] = psum;
    __syncthreads();
    if (w < 2)
      for (int et = 0; et < 8; et++)
        *(f32x4*)&Ored[w][et * 16 + l15][q * 4] = O[et];
    __syncthreads();
    if (w >= 2)
      for (int et = 0; et < 8; et++) {
        f32x4 acc = *(const f32x4*)&Ored[w - 2][et * 16 + l15][q * 4];
        acc += O[et];
        *(f32x4*)&Ored[w - 2][et * 16 + l15][q * 4] = acc;
      }
    __syncthreads();
    {
      int e = threadIdx.x & 127, half = threadIdx.x >> 7;
      f32x4 s0 = *(const f32x4*)&Ored[0][e][half * 8];
      f32x4 s1 = *(const f32x4*)&Ored[0][e][half * 8 + 4];
      s0 += *(const f32x4*)&Ored[1][e][half * 8];
      s1 += *(const f32x4*)&Ored[1][e][half * 8 + 4];
      for (int i = 0; i < 8; i++) {
        int row = half * 8 + i;
        float tot = psL[0][row] + psL[1][row] + psL[2][row] + psL[3][row];
        float val = (i < 4 ? s0[i] : s1[i - 4]) / tot;
        long off = (qb + row) * 2048 + h * 128 + e;
        o_comb[off] = f2b(0.5f * val + 0.5f * b2f(o_lin[off]));
      }
    }
    __syncthreads();
  }
}

// ---------------- launch ----------------
extern "C" void kernel_launch(void* const* d_in, const int* in_sizes, int n_in,
                              void* d_out, int out_size, void* d_ws, size_t ws_size,
                              hipStream_t stream) {
  const float* hs = (const float*)d_in[0];
  const float* wq = (const float*)d_in[1];
  const float* wk = (const float*)d_in[2];
  const float* wv = (const float*)d_in[3];
  const float* wo = (const float*)d_in[4];

  char* p = (char*)d_ws;
  auto alloc = [&](size_t bytes) {
    char* r = p;
    p += (bytes + 255) & ~(size_t)255;
    return r;
  };
  u16* hsb    = (u16*)alloc(16777216);   // reused as o_comb
  u16* wqkvT  = (u16*)alloc(12582912);
  u16* woT    = (u16*)alloc(8388608);
  u16* qkv    = (u16*)alloc(25165824);
  u16* qsb    = (u16*)alloc(16777216);
  u16* ksb    = (u16*)alloc(4194304);
  u16* kbb    = (u16*)alloc(4194304);
  u16* kbT    = (u16*)alloc(4194304);
  u16* vTb    = (u16*)alloc(4194304);
  u16* o_lin  = (u16*)alloc(16777216);
  u16* W_g    = (u16*)alloc(4194304);
  u16* U0_g   = (u16*)alloc(4194304);
  u16* M_g    = (u16*)alloc(8388608);
  float* NTT_g = (float*)alloc(16777216);
  u16* St0_g  = (u16*)alloc(8388608);
  u16* UT_g   = (u16*)alloc(4194304);

  k_prep0<<<4608, 256, 0, stream>>>(hs, wq, wk, wv, wo, hsb, wqkvT, woT);
  k_gemm<0><<<dim3(24, 32), 256, 0, stream>>>(hsb, wqkvT, qkv, 4096, 3072, 2048);
  k_act<<<1536, 256, 0, stream>>>(qkv, qsb, ksb, kbb, kbT, vTb);
  k_phase1<<<256, 256, 0, stream>>>(ksb, kbb, kbT, qkv, W_g, U0_g, M_g, NTT_g);
  k_phase2<<<64, 256, 0, stream>>>(W_g, U0_g, M_g, NTT_g, St0_g, UT_g);
  k_phase3<<<1024, 256, 0, stream>>>(qsb, kbb, St0_g, UT_g, o_lin);
  k_flash<<<2048, 256, 0, stream>>>(qkv, vTb, o_lin, hsb);
  k_gemm<1><<<dim3(16, 32), 256, 0, stream>>>(hsb, woT, (float*)d_out, 4096, 2048, 2048);
}

// Round 5
// 522.153 us; speedup vs baseline: 1.2484x; 1.2484x over previous
//
#include <hip/hip_runtime.h>

// LiZAttention: gated delta-rule linear attention + causal softmax attention,
// shared QKV / output projections. B=2, N=2048, D=2048, H=16, KVH=4, HD=128.

typedef unsigned short u16;
typedef short bf16x8 __attribute__((ext_vector_type(8)));
typedef float f32x4 __attribute__((ext_vector_type(4)));

#define DEV static __device__ __forceinline__

DEV f32x4 mfma(bf16x8 a, bf16x8 b, f32x4 c) {
  return __builtin_amdgcn_mfma_f32_16x16x32_bf16(a, b, c, 0, 0, 0);
}
DEV u16 f2b(float f) {
  unsigned int u = __builtin_bit_cast(unsigned int, f);
  u = (u + 0x7FFF + ((u >> 16) & 1)) >> 16;
  return (u16)u;
}
DEV float b2f(u16 b) {
  unsigned int u = ((unsigned int)b) << 16;
  return __builtin_bit_cast(float, u);
}
DEV unsigned packbf(float a, float b) {
  unsigned ua = __builtin_bit_cast(unsigned, a) + 0x8000u;
  unsigned ub = __builtin_bit_cast(unsigned, b) + 0x8000u;
  return (ua >> 16) | (ub & 0xffff0000u);
}
DEV float logsig(float x) { return fminf(x, 0.f) - log1pf(__expf(-fabsf(x))); }

DEV void gll16(const u16* g, u16* l) {
  __builtin_amdgcn_global_load_lds(
      (const __attribute__((address_space(1))) void*)g,
      (__attribute__((address_space(3))) void*)l, 16, 0, 0);
}

// ---------------- prep0: hs cast + tiled weight transposes ----------------
__global__ __launch_bounds__(256) void k_prep0(const float* __restrict__ hs,
    const float* __restrict__ wq, const float* __restrict__ wk,
    const float* __restrict__ wv, const float* __restrict__ wo,
    u16* __restrict__ hsb, u16* __restrict__ wqkvT, u16* __restrict__ woT) {
  int bid = blockIdx.x;
  int t = threadIdx.x;
  if (bid < 2048) {
    for (int it = 0; it < 4; it++) {
      long i = (long)bid * 4096 + it * 1024 + t * 4;
      const float4 v = *(const float4*)&hs[i];
      u16 o[4] = {f2b(v.x), f2b(v.y), f2b(v.z), f2b(v.w)};
      *(uint2*)&hsb[i] = *(const uint2*)o;
    }
    return;
  }
  bid -= 2048;
  __shared__ u16 T[64][72];
  const float* s; int sLD; long c0; u16* d; int nb, kb;
  if (bid < 1536) {
    int tn = bid >> 5, tk = bid & 31;
    nb = tn * 64; kb = tk * 64; d = wqkvT;
    if (nb < 2048)      { s = wq; sLD = 2048; c0 = nb; }
    else if (nb < 2560) { s = wk; sLD = 512;  c0 = nb - 2048; }
    else                { s = wv; sLD = 512;  c0 = nb - 2560; }
  } else {
    int b2 = bid - 1536;
    int tn = b2 >> 5, tk = b2 & 31;
    nb = tn * 64; kb = tk * 64; d = woT; s = wo; sLD = 2048; c0 = nb;
  }
  int lr = t >> 4, lc = (t & 15) * 4;
  for (int it = 0; it < 4; it++) {
    int r = lr + it * 16;
    float4 v = *(const float4*)&s[(long)(kb + r) * sLD + c0 + lc];
    u16 o[4] = {f2b(v.x), f2b(v.y), f2b(v.z), f2b(v.w)};
    *(uint2*)&T[r][lc] = *(const uint2*)o;
  }
  __syncthreads();
  int nl = t >> 2, kc = (t & 3) * 16;
  u16 pk[16];
  for (int i = 0; i < 16; i++) pk[i] = T[kc + i][nl];
  u16* dp = &d[(long)(nb + nl) * 2048 + kb + kc];
  *(uint4*)dp = *(const uint4*)pk;
  *(uint4*)(dp + 8) = *(const uint4*)(pk + 8);
}

// ---------------- GEMM (m97 structure): C[M][N] = A[M][K] * Bt[N][K]^T --------
template <int OUT_F32>
__global__ __launch_bounds__(256) void k_gemm(const u16* __restrict__ A,
    const u16* __restrict__ Bt, void* __restrict__ Cout, int M, int N, int K) {
  __shared__ u16 As[8192];
  __shared__ u16 Bs[8192];
  int t = threadIdx.x;
  int w = t >> 6, ln = t & 63, l15 = ln & 15, q = ln >> 4;
  long rb = (long)blockIdx.y * 128, cb = (long)blockIdx.x * 128;
  int wm = (w >> 1) * 64, wn = (w & 1) * 64;
  f32x4 acc[4][4] = {};
  int sr = t >> 3, sc = (t & 7) << 3;
  const u16* Ag = &A[(rb + sr) * (long)K + sc];
  const u16* Bg = &Bt[(cb + sr) * (long)K + sc];
  u16* Asl = &As[t * 8];
  u16* Bsl = &Bs[t * 8];
  for (int k0 = 0; k0 < K; k0 += 64) {
    __syncthreads();
    for (int it = 0; it < 4; it++) {
      gll16(Ag + (long)it * 32 * K + k0, Asl + it * 2048);
      gll16(Bg + (long)it * 32 * K + k0, Bsl + it * 2048);
    }
    __syncthreads();
    for (int ks = 0; ks < 2; ks++) {
      bf16x8 af[4], bfr[4];
      for (int mt = 0; mt < 4; mt++)
        af[mt] = *(const bf16x8*)&As[(wm + mt * 16 + l15) * 64 + ks * 32 + q * 8];
      for (int nt = 0; nt < 4; nt++)
        bfr[nt] = *(const bf16x8*)&Bs[(wn + nt * 16 + l15) * 64 + ks * 32 + q * 8];
      for (int mt = 0; mt < 4; mt++)
        for (int nt = 0; nt < 4; nt++)
          acc[mt][nt] = mfma(af[mt], bfr[nt], acc[mt][nt]);
    }
  }
  for (int mt = 0; mt < 4; mt++)
    for (int nt = 0; nt < 4; nt++)
      for (int r = 0; r < 4; r++) {
        long m = rb + wm + mt * 16 + q * 4 + r;
        long n = cb + wn + nt * 16 + l15;
        if (OUT_F32) ((float*)Cout)[m * N + n] = acc[mt][nt][r];
        else ((u16*)Cout)[m * N + n] = f2b(acc[mt][nt][r]);
      }
}

// ---------------- k_act: q softmax + k softmax/beta (+kbT) + vT -------------
__global__ __launch_bounds__(256) void k_act(const u16* __restrict__ qkv,
    u16* __restrict__ qsb, u16* __restrict__ ksb, u16* __restrict__ kbb,
    u16* __restrict__ kbT, u16* __restrict__ vTb) {
  __shared__ u16 T[128][72];
  int bid = blockIdx.x, t = threadIdx.x;
  const float L2E = 1.442695041f;
  if (bid < 1024) {
    int h = bid & 15;
    long rb = (long)(bid >> 4) * 64;
    int row = t >> 2, c = (t & 3) * 32;
    const u16* src = &qkv[(rb + row) * 3072 + h * 128 + c];
    float x[32];
    for (int i = 0; i < 4; i++) {
      uint4 v = *(const uint4*)&src[i * 8];
      unsigned vv[4] = {v.x, v.y, v.z, v.w};
      for (int jj = 0; jj < 4; jj++) {
        x[i * 8 + jj * 2] = b2f((u16)(vv[jj] & 0xffff));
        x[i * 8 + jj * 2 + 1] = b2f((u16)(vv[jj] >> 16));
      }
    }
    float mx = x[0];
    for (int i = 1; i < 32; i++) mx = fmaxf(mx, x[i]);
    mx = fmaxf(mx, __shfl_xor(mx, 1));
    mx = fmaxf(mx, __shfl_xor(mx, 2));
    float sm = 0.f;
    for (int i = 0; i < 32; i++) { x[i] = exp2f((x[i] - mx) * L2E); sm += x[i]; }
    sm += __shfl_xor(sm, 1);
    sm += __shfl_xor(sm, 2);
    float inv = 1.f / sm;
    unsigned pk[16];
    for (int i = 0; i < 16; i++) pk[i] = packbf(x[2 * i] * inv, x[2 * i + 1] * inv);
    u16* dst = &qsb[(rb + row) * 2048 + h * 128 + c];
    for (int i = 0; i < 4; i++) *(uint4*)&dst[i * 8] = *(const uint4*)&pk[i * 4];
    return;
  }
  int idx = bid - 1024;
  int isV = idx >= 256;
  if (isV) idx -= 256;
  int kvg = idx & 3;
  long rb = (long)(idx >> 2) * 64;
  int row = t >> 2, c = (t & 3) * 32;
  int b = (int)(rb >> 11);
  int c8 = b * 4 + kvg;
  long nloc = rb & 2047;
  if (!isV) {
    const u16* src = &qkv[(rb + row) * 3072 + 2048 + kvg * 128 + c];
    float x[32];
    for (int i = 0; i < 4; i++) {
      uint4 v = *(const uint4*)&src[i * 8];
      unsigned vv[4] = {v.x, v.y, v.z, v.w};
      for (int jj = 0; jj < 4; jj++) {
        x[i * 8 + jj * 2] = b2f((u16)(vv[jj] & 0xffff));
        x[i * 8 + jj * 2 + 1] = b2f((u16)(vv[jj] >> 16));
      }
    }
    float bt[32];
    for (int i = 0; i < 32; i++) bt[i] = exp2f(logsig(x[i]) * 0.0901684411f);
    float mx = x[0];
    for (int i = 1; i < 32; i++) mx = fmaxf(mx, x[i]);
    mx = fmaxf(mx, __shfl_xor(mx, 1));
    mx = fmaxf(mx, __shfl_xor(mx, 2));
    float sm = 0.f;
    for (int i = 0; i < 32; i++) { x[i] = exp2f((x[i] - mx) * L2E); sm += x[i]; }
    sm += __shfl_xor(sm, 1);
    sm += __shfl_xor(sm, 2);
    float inv = 1.f / sm;
    unsigned pks[16], pkb[16];
    for (int i = 0; i < 16; i++) {
      float s0 = x[2 * i] * inv, s1 = x[2 * i + 1] * inv;
      pks[i] = packbf(s0, s1);
      pkb[i] = packbf(s0 * bt[2 * i], s1 * bt[2 * i + 1]);
    }
    u16* d1 = &ksb[(rb + row) * 512 + kvg * 128 + c];
    u16* d2 = &kbb[(rb + row) * 512 + kvg * 128 + c];
    for (int i = 0; i < 4; i++) {
      *(uint4*)&d1[i * 8] = *(const uint4*)&pks[i * 4];
      *(uint4*)&d2[i * 8] = *(const uint4*)&pkb[i * 4];
    }
    for (int i = 0; i < 16; i++) {
      T[c + 2 * i][row] = (u16)(pkb[i] & 0xffff);
      T[c + 2 * i + 1][row] = (u16)(pkb[i] >> 16);
    }
  } else {
    const u16* src = &qkv[(rb + row) * 3072 + 2560 + kvg * 128 + c];
    for (int i = 0; i < 4; i++) {
      uint4 v = *(const uint4*)&src[i * 8];
      unsigned vv[4] = {v.x, v.y, v.z, v.w};
      for (int jj = 0; jj < 4; jj++) {
        T[c + i * 8 + jj * 2][row] = (u16)(vv[jj] & 0xffff);
        T[c + i * 8 + jj * 2 + 1][row] = (u16)(vv[jj] >> 16);
      }
    }
  }
  __syncthreads();
  int dr = t >> 1, nc = (t & 1) * 32;
  u16* dst = isV ? vTb : kbT;
  u16* dp = &dst[((long)(c8 * 128 + dr)) * 2048 + nloc + nc];
  for (int i = 0; i < 4; i++)
    *(uint4*)&dp[i * 8] = *(const uint4*)&T[dr][nc + i * 8];
}

// ---------------- delta-rule phase 1 ----------------
__global__ __launch_bounds__(256) void k_phase1(const u16* __restrict__ ksb,
    const u16* __restrict__ kbb, const u16* __restrict__ kbT,
    const u16* __restrict__ qkv, u16* __restrict__ W_g, u16* __restrict__ U0_g,
    u16* __restrict__ M_g, float* __restrict__ NTT_g) {
  __shared__ u16 Pm[64][72];
  __shared__ u16 PT[64][72];
  __shared__ u16 slab[4][64][72];
  int cc = blockIdx.x;
  int c8 = cc >> 5, j = cc & 31;
  int b = c8 >> 2, kv = c8 & 3;
  long rb = (long)b * 2048 + j * 64;
  int w = threadIdx.x >> 6, ln = threadIdx.x & 63, l15 = ln & 15, q = ln >> 4;
  {
    f32x4 a4[4] = {};
    int m0 = w * 16;
    for (int ks = 0; ks < 4; ks++) {
      bf16x8 af = *(const bf16x8*)&ksb[(rb + m0 + l15) * 512 + kv * 128 + ks * 32 + q * 8];
      for (int nt = 0; nt < 4; nt++) {
        bf16x8 bfr = *(const bf16x8*)&kbb[(rb + nt * 16 + l15) * 512 + kv * 128 + ks * 32 + q * 8];
        a4[nt] = mfma(af, bfr, a4[nt]);
      }
    }
    for (int nt = 0; nt < 4; nt++)
      for (int r = 0; r < 4; r++) {
        int m = m0 + q * 4 + r, n = nt * 16 + l15;
        u16 h = f2b((m > n) ? -a4[nt][r] : 0.f);
        Pm[m][n] = h; PT[n][m] = h;
      }
  }
  for (int idx = threadIdx.x; idx < 16384; idx += 256) {
    int s = idx >> 12, rem = idx & 4095, t = rem >> 6, c = rem & 63;
    u16 v;
    if (s < 2) v = ksb[(rb + t) * 512 + kv * 128 + s * 64 + c];
    else       v = qkv[(rb + t) * 3072 + 2560 + kv * 128 + (s - 2) * 64 + c];
    slab[s][c][t] = v;
  }
  __syncthreads();
  f32x4 X[4][4];
  for (int mt = 0; mt < 4; mt++)
    for (int nt = 0; nt < 4; nt++)
      for (int r = 0; r < 4; r++)
        X[mt][nt][r] = b2f(slab[w][nt * 16 + l15][mt * 16 + q * 4 + r]);
  for (int f = 0; f < 6; f++) {
    for (int ks = 0; ks < 2; ks++) {
      bf16x8 af[4], bfr[4];
      for (int mt = 0; mt < 4; mt++)
        af[mt] = *(const bf16x8*)&Pm[mt * 16 + l15][ks * 32 + q * 8];
      for (int nt = 0; nt < 4; nt++)
        bfr[nt] = *(const bf16x8*)&slab[w][nt * 16 + l15][ks * 32 + q * 8];
      for (int mt = 0; mt < 4; mt++)
        for (int nt = 0; nt < 4; nt++)
          X[mt][nt] = mfma(af[mt], bfr[nt], X[mt][nt]);
    }
    f32x4 pn[4] = {};
    if (f < 5) {
      int m0 = w * 16;
      for (int ks = 0; ks < 2; ks++) {
        bf16x8 af = *(const bf16x8*)&Pm[m0 + l15][ks * 32 + q * 8];
        for (int nt = 0; nt < 4; nt++) {
          bf16x8 bfr = *(const bf16x8*)&PT[nt * 16 + l15][ks * 32 + q * 8];
          pn[nt] = mfma(af, bfr, pn[nt]);
        }
      }
    }
    __syncthreads();
    for (int mt = 0; mt < 4; mt++)
      for (int nt = 0; nt < 4; nt++)
        for (int r = 0; r < 4; r++)
          slab[w][nt * 16 + l15][mt * 16 + q * 4 + r] = f2b(X[mt][nt][r]);
    if (f < 5) {
      int m0 = w * 16;
      for (int nt = 0; nt < 4; nt++)
        for (int r = 0; r < 4; r++) {
          int m = m0 + q * 4 + r, n = nt * 16 + l15;
          u16 h = f2b(pn[nt][r]);
          Pm[m][n] = h; PT[n][m] = h;
        }
    }
    __syncthreads();
  }
  for (int idx = threadIdx.x; idx < 8192; idx += 256) {
    int t = idx >> 7, d = idx & 127;
    W_g[(long)cc * 8192 + idx] = slab[d >> 6][d & 63][t];
  }
  for (int idx = threadIdx.x; idx < 8192; idx += 256) {
    int t = idx >> 7, e = idx & 127;
    U0_g[(long)cc * 8192 + idx] = slab[2 + (e >> 6)][e & 63][t];
  }
  {
    f32x4 acc[2][8] = {};
    int m0 = w * 32;
    for (int ks = 0; ks < 2; ks++) {
      bf16x8 af[2], bfr[8];
      for (int mt = 0; mt < 2; mt++)
        af[mt] = *(const bf16x8*)&kbT[((long)(c8 * 128 + m0 + mt * 16 + l15)) * 2048 + j * 64 + ks * 32 + q * 8];
      for (int nt = 0; nt < 8; nt++) {
        int n = nt * 16 + l15;
        bfr[nt] = *(const bf16x8*)&slab[n >> 6][n & 63][ks * 32 + q * 8];
      }
      for (int mt = 0; mt < 2; mt++)
        for (int nt = 0; nt < 8; nt++)
          acc[mt][nt] = mfma(af[mt], bfr[nt], acc[mt][nt]);
    }
    for (int mt = 0; mt < 2; mt++)
      for (int nt = 0; nt < 8; nt++)
        for (int r = 0; r < 4; r++) {
          int i_ = m0 + mt * 16 + q * 4 + r, jj = nt * 16 + l15;
          M_g[(long)cc * 16384 + (long)i_ * 128 + jj] =
              f2b(((i_ == jj) ? 1.f : 0.f) - acc[mt][nt][r]);
        }
  }
  {
    f32x4 acc[2][8] = {};
    int m0 = w * 32;
    for (int ks = 0; ks < 2; ks++) {
      bf16x8 af[2], bfr[8];
      for (int mt = 0; mt < 2; mt++)
        af[mt] = *(const bf16x8*)&kbT[((long)(c8 * 128 + m0 + mt * 16 + l15)) * 2048 + j * 64 + ks * 32 + q * 8];
      for (int nt = 0; nt < 8; nt++) {
        int e = nt * 16 + l15;
        bfr[nt] = *(const bf16x8*)&slab[2 + (e >> 6)][e & 63][ks * 32 + q * 8];
      }
      for (int mt = 0; mt < 2; mt++)
        for (int nt = 0; nt < 8; nt++)
          acc[mt][nt] = mfma(af[mt], bfr[nt], acc[mt][nt]);
    }
    for (int mt = 0; mt < 2; mt++)
      for (int nt = 0; nt < 8; nt++)
        for (int r = 0; r < 4; r++) {
          int i_ = m0 + mt * 16 + q * 4 + r, e = nt * 16 + l15;
          NTT_g[(long)cc * 16384 + (long)i_ * 128 + e] = acc[mt][nt][r];
        }
  }
}

// ---------------- phase 2: sequential chunk scan, prefetched ----------------
struct P2Buf { bf16x8 W[4]; bf16x8 M[4][2]; f32x4 NT[2]; ushort4 U0; };

__global__ __launch_bounds__(256) void k_phase2(const u16* __restrict__ W_g,
    const u16* __restrict__ U0_g, const u16* __restrict__ M_g,
    const float* __restrict__ NTT_g, u16* __restrict__ St0_g,
    u16* __restrict__ UT_g) {
  __shared__ u16 St[16][136];
  int c8 = blockIdx.x & 7, eb = blockIdx.x >> 3;
  int e0 = eb * 16;
  int w = threadIdx.x >> 6, ln = threadIdx.x & 63, l15 = ln & 15, q = ln >> 4;
  for (int idx = threadIdx.x; idx < 16 * 128; idx += 256)
    St[idx >> 7][idx & 127] = 0;
  __syncthreads();

  auto loadbuf = [&](P2Buf& B, long cc) {
    for (int ks = 0; ks < 4; ks++)
      B.W[ks] = *(const bf16x8*)&W_g[cc * 8192 + (long)(w * 16 + l15) * 128 + ks * 32 + q * 8];
    for (int ks = 0; ks < 4; ks++)
      for (int nt = 0; nt < 2; nt++)
        B.M[ks][nt] = *(const bf16x8*)&M_g[cc * 16384 + (long)(w * 32 + nt * 16 + l15) * 128 + ks * 32 + q * 8];
    for (int nt = 0; nt < 2; nt++)
      B.NT[nt] = *(const f32x4*)&NTT_g[cc * 16384 + (long)(w * 32 + nt * 16 + l15) * 128 + e0 + q * 4];
    B.U0 = *(const ushort4*)&U0_g[cc * 8192 + (long)(w * 16 + l15) * 128 + e0 + q * 4];
  };

  auto step = [&](long cc, P2Buf& cur, P2Buf& nxt, bool pf) {
    if (pf) loadbuf(nxt, cc + 1);
    for (int idx = threadIdx.x; idx < 2048; idx += 256)
      St0_g[cc * 16384 + (long)(e0 + (idx >> 7)) * 128 + (idx & 127)] = St[idx >> 7][idx & 127];
    bf16x8 sf[4];
    for (int ks = 0; ks < 4; ks++)
      sf[ks] = *(const bf16x8*)&St[l15][ks * 32 + q * 8];
    f32x4 acc = {};
    for (int ks = 0; ks < 4; ks++) acc = mfma(sf[ks], cur.W[ks], acc);
    const u16* u0p = (const u16*)&cur.U0;
    for (int r = 0; r < 4; r++)
      UT_g[cc * 8192 + (long)(e0 + q * 4 + r) * 64 + w * 16 + l15] = f2b(b2f(u0p[r]) - acc[r]);
    f32x4 acc2[2] = {cur.NT[0], cur.NT[1]};
    for (int ks = 0; ks < 4; ks++)
      for (int nt = 0; nt < 2; nt++)
        acc2[nt] = mfma(sf[ks], cur.M[ks][nt], acc2[nt]);
    __syncthreads();
    for (int nt = 0; nt < 2; nt++)
      for (int r = 0; r < 4; r++)
        St[q * 4 + r][w * 32 + nt * 16 + l15] = f2b(acc2[nt][r]);
    __syncthreads();
  };

  P2Buf A, B;
  long base = (long)c8 * 32;
  loadbuf(A, base);
  for (int j = 0; j < 32; j += 2) {
    step(base + j, A, B, true);
    step(base + j + 1, B, A, j + 2 < 32);
  }
}

// ---------------- phase 3 ----------------
__global__ __launch_bounds__(256) void k_phase3(const u16* __restrict__ qsb,
    const u16* __restrict__ kbb, const u16* __restrict__ St0_g,
    const u16* __restrict__ UT_g, u16* __restrict__ o_lin) {
  __shared__ u16 Pl[64][72];
  int cc = blockIdx.x >> 2, hh = blockIdx.x & 3;
  int c8 = cc >> 5, j = cc & 31;
  int b = c8 >> 2, kv = c8 & 3, hq = kv * 4 + hh;
  long rb = (long)b * 2048 + j * 64;
  int w = threadIdx.x >> 6, ln = threadIdx.x & 63, l15 = ln & 15, q = ln >> 4;
  int m0 = w * 16;
  f32x4 O[8] = {};
  for (int ks = 0; ks < 4; ks++) {
    bf16x8 af = *(const bf16x8*)&qsb[(rb + m0 + l15) * 2048 + hq * 128 + ks * 32 + q * 8];
    for (int nt = 0; nt < 8; nt++) {
      bf16x8 bfr = *(const bf16x8*)&St0_g[(long)cc * 16384 + (long)(nt * 16 + l15) * 128 + ks * 32 + q * 8];
      O[nt] = mfma(af, bfr, O[nt]);
    }
  }
  {
    f32x4 p4[4] = {};
    for (int ks = 0; ks < 4; ks++) {
      bf16x8 af = *(const bf16x8*)&qsb[(rb + m0 + l15) * 2048 + hq * 128 + ks * 32 + q * 8];
      for (int nt = 0; nt < 4; nt++) {
        bf16x8 bfr = *(const bf16x8*)&kbb[(rb + nt * 16 + l15) * 512 + kv * 128 + ks * 32 + q * 8];
        p4[nt] = mfma(af, bfr, p4[nt]);
      }
    }
    for (int nt = 0; nt < 4; nt++)
      for (int r = 0; r < 4; r++) {
        int m = m0 + q * 4 + r, n = nt * 16 + l15;
        Pl[m][n] = f2b((m >= n) ? p4[nt][r] : 0.f);
      }
  }
  __syncthreads();
  for (int ks = 0; ks < 2; ks++) {
    bf16x8 af = *(const bf16x8*)&Pl[m0 + l15][ks * 32 + q * 8];
    for (int nt = 0; nt < 8; nt++) {
      bf16x8 bfr = *(const bf16x8*)&UT_g[(long)cc * 8192 + (long)(nt * 16 + l15) * 64 + ks * 32 + q * 8];
      O[nt] = mfma(af, bfr, O[nt]);
    }
  }
  for (int nt = 0; nt < 8; nt++)
    for (int r = 0; r < 4; r++) {
      int m = m0 + q * 4 + r, e = nt * 16 + l15;
      o_lin[(rb + m) * 2048 + hq * 128 + e] = f2b(O[nt][r]);
    }
}

// ---------------- flash: GEMM-style, 128-q tiles, LDS-staged K/V ------------
// Block = (b, h, pair{p, 15-p}): 256 blocks, 17 KV-tile units each, 1/CU.
// K double-buffered + V single-buffered in LDS via global_load_lds;
// waves q-split (32 rows); S^T = K·Q^T; P wave-private LDS; O in regs.
__global__ __launch_bounds__(256, 1) void k_flash(const u16* __restrict__ qkv,
    const u16* __restrict__ vTb, const u16* __restrict__ o_lin,
    u16* __restrict__ o_comb) {
  __shared__ u16 Ks[2][16384];   // [buf][k-row][d]
  __shared__ u16 Vs[16384];      // [e][n-local]
  __shared__ u16 P[4][32][136];  // [wave][q-local][k]
  int pr = blockIdx.x & 7, h = (blockIdx.x >> 3) & 15, b = blockIdx.x >> 7;
  int kv = h >> 2;
  int t = threadIdx.x;
  int w = t >> 6, ln = t & 63, l15 = ln & 15, qd = ln >> 4;
  const float sc2 = 0.127517444f;  // (1/sqrt(128)) * log2(e)
  long kvb = (long)b * 2048;
  const u16* Kgb = &qkv[(kvb) * 3072 + 2048 + kv * 128];
  const u16* Vgb = &vTb[(long)(b * 4 + kv) * 128 * 2048];
  // gll staging addresses for this thread (8 calls of 4KB each per 32KB tile)
  int srow = t >> 4, scol = (t & 15) * 8;
  u16 (*Pw)[136] = P[w];

  for (int sel = 0; sel < 2; sel++) {
    int qt = sel ? 15 - pr : pr;
    long qb = kvb + qt * 128;
    int njt = qt + 1;
    // Q fragments: wave w owns q-rows w*32 .. w*32+31
    bf16x8 bq[2][4];
    for (int nt = 0; nt < 2; nt++)
      for (int ks = 0; ks < 4; ks++)
        bq[nt][ks] = *(const bf16x8*)&qkv[(qb + w * 32 + nt * 16 + l15) * 3072 + h * 128 + ks * 32 + qd * 8];
    __syncthreads();  // Ks[0] free (prev sel done)
    // prologue: stage K(0)
    for (int i = 0; i < 8; i++)
      gll16(Kgb + (long)(i * 16 + srow) * 3072 + scol, &Ks[0][i * 2048 + t * 8]);
    f32x4 O[2][8] = {};
    float psum[2] = {0.f, 0.f};
    for (int jt = 0; jt < njt; jt++) {
      __syncthreads();  // K(jt) staged; V free; K[(jt+1)&1] free
      // issue V(jt) and K(jt+1)
      for (int i = 0; i < 8; i++)
        gll16(Vgb + (long)(i * 16 + srow) * 2048 + jt * 128 + scol, &Vs[i * 2048 + t * 8]);
      if (jt + 1 < njt) {
        const u16* Kg = Kgb + (long)(jt + 1) * 128 * 3072;
        u16* Kd = &Ks[(jt + 1) & 1][0];
        for (int i = 0; i < 8; i++)
          gll16(Kg + (long)(i * 16 + srow) * 3072 + scol, &Kd[i * 2048 + t * 8]);
      }
      // S^T = K(jt) · Q^T  (wave computes all 128 k x its 32 q)
      const u16* Kc = &Ks[jt & 1][0];
      f32x4 st[8][2] = {};
      for (int ks = 0; ks < 4; ks++)
        for (int mt = 0; mt < 8; mt++) {
          bf16x8 ak = *(const bf16x8*)&Kc[(mt * 16 + l15) * 128 + ks * 32 + qd * 8];
          st[mt][0] = mfma(ak, bq[0][ks], st[mt][0]);
          st[mt][1] = mfma(ak, bq[1][ks], st[mt][1]);
        }
      // exp + causal mask + psum + P write (wave-private)
      bool last = (jt == njt - 1);
      for (int nt = 0; nt < 2; nt++) {
        int rg = qt * 128 + w * 32 + nt * 16 + l15;
        for (int mt = 0; mt < 8; mt++) {
          f32x4 v = st[mt][nt];
          float pv[4];
          for (int r = 0; r < 4; r++) {
            float p = exp2f(v[r] * sc2);
            int kg = jt * 128 + mt * 16 + qd * 4 + r;
            if (last && kg > rg) p = 0.f;
            pv[r] = p;
            psum[nt] += p;
          }
          unsigned pu[2] = {packbf(pv[0], pv[1]), packbf(pv[2], pv[3])};
          *(uint2*)&Pw[nt * 16 + l15][mt * 16 + qd * 4] = *(const uint2*)pu;
        }
      }
      __syncthreads();  // drains V(jt) (+K(jt+1)); vmcnt covered by QK above
      // O += P · V
      bf16x8 ap[2][4];
      for (int mt2 = 0; mt2 < 2; mt2++)
        for (int ks = 0; ks < 4; ks++)
          ap[mt2][ks] = *(const bf16x8*)&Pw[mt2 * 16 + l15][ks * 32 + qd * 8];
      for (int ks = 0; ks < 4; ks++)
        for (int et = 0; et < 8; et++) {
          bf16x8 bv = *(const bf16x8*)&Vs[(et * 16 + l15) * 128 + ks * 32 + qd * 8];
          O[0][et] = mfma(ap[0][ks], bv, O[0][et]);
          O[1][et] = mfma(ap[1][ks], bv, O[1][et]);
        }
    }
    // psum reduce over quads -> all lanes hold full row sums
    for (int nt = 0; nt < 2; nt++) {
      psum[nt] += __shfl_xor(psum[nt], 16);
      psum[nt] += __shfl_xor(psum[nt], 32);
    }
    // normalize + combine + store
    for (int mt2 = 0; mt2 < 2; mt2++)
      for (int r = 0; r < 4; r++) {
        float linv = 1.f / __shfl(psum[mt2], qd * 4 + r);
        int rowg = w * 32 + mt2 * 16 + qd * 4 + r;
        for (int et = 0; et < 8; et++) {
          long off = (qb + rowg) * 2048 + h * 128 + et * 16 + l15;
          o_comb[off] = f2b(0.5f * O[mt2][et][r] * linv + 0.5f * b2f(o_lin[off]));
        }
      }
  }
}

// ---------------- launch ----------------
extern "C" void kernel_launch(void* const* d_in, const int* in_sizes, int n_in,
                              void* d_out, int out_size, void* d_ws, size_t ws_size,
                              hipStream_t stream) {
  const float* hs = (const float*)d_in[0];
  const float* wq = (const float*)d_in[1];
  const float* wk = (const float*)d_in[2];
  const float* wv = (const float*)d_in[3];
  const float* wo = (const float*)d_in[4];

  char* p = (char*)d_ws;
  auto alloc = [&](size_t bytes) {
    char* r = p;
    p += (bytes + 255) & ~(size_t)255;
    return r;
  };
  u16* hsb    = (u16*)alloc(16777216);   // reused as o_comb
  u16* wqkvT  = (u16*)alloc(12582912);
  u16* woT    = (u16*)alloc(8388608);
  u16* qkv    = (u16*)alloc(25165824);
  u16* qsb    = (u16*)alloc(16777216);
  u16* ksb    = (u16*)alloc(4194304);
  u16* kbb    = (u16*)alloc(4194304);
  u16* kbT    = (u16*)alloc(4194304);
  u16* vTb    = (u16*)alloc(4194304);
  u16* o_lin  = (u16*)alloc(16777216);
  u16* W_g    = (u16*)alloc(4194304);
  u16* U0_g   = (u16*)alloc(4194304);
  u16* M_g    = (u16*)alloc(8388608);
  float* NTT_g = (float*)alloc(16777216);
  u16* St0_g  = (u16*)alloc(8388608);
  u16* UT_g   = (u16*)alloc(4194304);

  k_prep0<<<4608, 256, 0, stream>>>(hs, wq, wk, wv, wo, hsb, wqkvT, woT);
  k_gemm<0><<<dim3(24, 32), 256, 0, stream>>>(hsb, wqkvT, qkv, 4096, 3072, 2048);
  k_act<<<1536, 256, 0, stream>>>(qkv, qsb, ksb, kbb, kbT, vTb);
  k_phase1<<<256, 256, 0, stream>>>(ksb, kbb, kbT, qkv, W_g, U0_g, M_g, NTT_g);
  k_phase2<<<64, 256, 0, stream>>>(W_g, U0_g, M_g, NTT_g, St0_g, UT_g);
  k_phase3<<<1024, 256, 0, stream>>>(qsb, kbb, St0_g, UT_g, o_lin);
  k_flash<<<256, 256, 0, stream>>>(qkv, vTb, o_lin, hsb);
  k_gemm<1><<<dim3(16, 32), 256, 0, stream>>>(hsb, woT, (float*)d_out, 4096, 2048, 2048);
}

// Round 6
// 505.202 us; speedup vs baseline: 1.2903x; 1.0336x over previous
//
#include <hip/hip_runtime.h>

// LiZAttention: gated delta-rule linear attention + causal softmax attention,
// shared QKV / output projections. B=2, N=2048, D=2048, H=16, KVH=4, HD=128.

typedef unsigned short u16;
typedef short bf16x8 __attribute__((ext_vector_type(8)));
typedef float f32x4 __attribute__((ext_vector_type(4)));

#define DEV static __device__ __forceinline__

DEV f32x4 mfma(bf16x8 a, bf16x8 b, f32x4 c) {
  return __builtin_amdgcn_mfma_f32_16x16x32_bf16(a, b, c, 0, 0, 0);
}
DEV u16 f2b(float f) {
  unsigned int u = __builtin_bit_cast(unsigned int, f);
  u = (u + 0x7FFF + ((u >> 16) & 1)) >> 16;
  return (u16)u;
}
DEV float b2f(u16 b) {
  unsigned int u = ((unsigned int)b) << 16;
  return __builtin_bit_cast(float, u);
}
DEV unsigned packbf(float a, float b) {
  unsigned ua = __builtin_bit_cast(unsigned, a) + 0x8000u;
  unsigned ub = __builtin_bit_cast(unsigned, b) + 0x8000u;
  return (ua >> 16) | (ub & 0xffff0000u);
}
DEV float logsig(float x) { return fminf(x, 0.f) - log1pf(__expf(-fabsf(x))); }

DEV void gll16(const u16* g, u16* l) {
  __builtin_amdgcn_global_load_lds(
      (const __attribute__((address_space(1))) void*)g,
      (__attribute__((address_space(3))) void*)l, 16, 0, 0);
}

// ---------------- prep0: hs cast + tiled weight transposes ----------------
__global__ __launch_bounds__(256) void k_prep0(const float* __restrict__ hs,
    const float* __restrict__ wq, const float* __restrict__ wk,
    const float* __restrict__ wv, const float* __restrict__ wo,
    u16* __restrict__ hsb, u16* __restrict__ wqkvT, u16* __restrict__ woT) {
  int bid = blockIdx.x;
  int t = threadIdx.x;
  if (bid < 2048) {
    for (int it = 0; it < 4; it++) {
      long i = (long)bid * 4096 + it * 1024 + t * 4;
      const float4 v = *(const float4*)&hs[i];
      u16 o[4] = {f2b(v.x), f2b(v.y), f2b(v.z), f2b(v.w)};
      *(uint2*)&hsb[i] = *(const uint2*)o;
    }
    return;
  }
  bid -= 2048;
  __shared__ u16 T[64][72];
  const float* s; int sLD; long c0; u16* d; int nb, kb;
  if (bid < 1536) {
    int tn = bid >> 5, tk = bid & 31;
    nb = tn * 64; kb = tk * 64; d = wqkvT;
    if (nb < 2048)      { s = wq; sLD = 2048; c0 = nb; }
    else if (nb < 2560) { s = wk; sLD = 512;  c0 = nb - 2048; }
    else                { s = wv; sLD = 512;  c0 = nb - 2560; }
  } else {
    int b2 = bid - 1536;
    int tn = b2 >> 5, tk = b2 & 31;
    nb = tn * 64; kb = tk * 64; d = woT; s = wo; sLD = 2048; c0 = nb;
  }
  int lr = t >> 4, lc = (t & 15) * 4;
  for (int it = 0; it < 4; it++) {
    int r = lr + it * 16;
    float4 v = *(const float4*)&s[(long)(kb + r) * sLD + c0 + lc];
    u16 o[4] = {f2b(v.x), f2b(v.y), f2b(v.z), f2b(v.w)};
    *(uint2*)&T[r][lc] = *(const uint2*)o;
  }
  __syncthreads();
  int nl = t >> 2, kc = (t & 3) * 16;
  u16 pk[16];
  for (int i = 0; i < 16; i++) pk[i] = T[kc + i][nl];
  u16* dp = &d[(long)(nb + nl) * 2048 + kb + kc];
  *(uint4*)dp = *(const uint4*)pk;
  *(uint4*)(dp + 8) = *(const uint4*)(pk + 8);
}

// ---------------- GEMM (m97 structure): C[M][N] = A[M][K] * Bt[N][K]^T --------
template <int OUT_F32>
__global__ __launch_bounds__(256) void k_gemm(const u16* __restrict__ A,
    const u16* __restrict__ Bt, void* __restrict__ Cout, int M, int N, int K) {
  __shared__ u16 As[8192];
  __shared__ u16 Bs[8192];
  int t = threadIdx.x;
  int w = t >> 6, ln = t & 63, l15 = ln & 15, q = ln >> 4;
  long rb = (long)blockIdx.y * 128, cb = (long)blockIdx.x * 128;
  int wm = (w >> 1) * 64, wn = (w & 1) * 64;
  f32x4 acc[4][4] = {};
  int sr = t >> 3, sc = (t & 7) << 3;
  const u16* Ag = &A[(rb + sr) * (long)K + sc];
  const u16* Bg = &Bt[(cb + sr) * (long)K + sc];
  u16* Asl = &As[t * 8];
  u16* Bsl = &Bs[t * 8];
  for (int k0 = 0; k0 < K; k0 += 64) {
    __syncthreads();
    for (int it = 0; it < 4; it++) {
      gll16(Ag + (long)it * 32 * K + k0, Asl + it * 2048);
      gll16(Bg + (long)it * 32 * K + k0, Bsl + it * 2048);
    }
    __syncthreads();
    for (int ks = 0; ks < 2; ks++) {
      bf16x8 af[4], bfr[4];
      for (int mt = 0; mt < 4; mt++)
        af[mt] = *(const bf16x8*)&As[(wm + mt * 16 + l15) * 64 + ks * 32 + q * 8];
      for (int nt = 0; nt < 4; nt++)
        bfr[nt] = *(const bf16x8*)&Bs[(wn + nt * 16 + l15) * 64 + ks * 32 + q * 8];
      for (int mt = 0; mt < 4; mt++)
        for (int nt = 0; nt < 4; nt++)
          acc[mt][nt] = mfma(af[mt], bfr[nt], acc[mt][nt]);
    }
  }
  for (int mt = 0; mt < 4; mt++)
    for (int nt = 0; nt < 4; nt++)
      for (int r = 0; r < 4; r++) {
        long m = rb + wm + mt * 16 + q * 4 + r;
        long n = cb + wn + nt * 16 + l15;
        if (OUT_F32) ((float*)Cout)[m * N + n] = acc[mt][nt][r];
        else ((u16*)Cout)[m * N + n] = f2b(acc[mt][nt][r]);
      }
}

// ---------------- k_act: q softmax + k softmax/beta (+kbT) + vT -------------
__global__ __launch_bounds__(256) void k_act(const u16* __restrict__ qkv,
    u16* __restrict__ qsb, u16* __restrict__ ksb, u16* __restrict__ kbb,
    u16* __restrict__ kbT, u16* __restrict__ vTb) {
  __shared__ u16 T[128][72];
  int bid = blockIdx.x, t = threadIdx.x;
  const float L2E = 1.442695041f;
  if (bid < 1024) {
    int h = bid & 15;
    long rb = (long)(bid >> 4) * 64;
    int row = t >> 2, c = (t & 3) * 32;
    const u16* src = &qkv[(rb + row) * 3072 + h * 128 + c];
    float x[32];
    for (int i = 0; i < 4; i++) {
      uint4 v = *(const uint4*)&src[i * 8];
      unsigned vv[4] = {v.x, v.y, v.z, v.w};
      for (int jj = 0; jj < 4; jj++) {
        x[i * 8 + jj * 2] = b2f((u16)(vv[jj] & 0xffff));
        x[i * 8 + jj * 2 + 1] = b2f((u16)(vv[jj] >> 16));
      }
    }
    float mx = x[0];
    for (int i = 1; i < 32; i++) mx = fmaxf(mx, x[i]);
    mx = fmaxf(mx, __shfl_xor(mx, 1));
    mx = fmaxf(mx, __shfl_xor(mx, 2));
    float sm = 0.f;
    for (int i = 0; i < 32; i++) { x[i] = exp2f((x[i] - mx) * L2E); sm += x[i]; }
    sm += __shfl_xor(sm, 1);
    sm += __shfl_xor(sm, 2);
    float inv = 1.f / sm;
    unsigned pk[16];
    for (int i = 0; i < 16; i++) pk[i] = packbf(x[2 * i] * inv, x[2 * i + 1] * inv);
    u16* dst = &qsb[(rb + row) * 2048 + h * 128 + c];
    for (int i = 0; i < 4; i++) *(uint4*)&dst[i * 8] = *(const uint4*)&pk[i * 4];
    return;
  }
  int idx = bid - 1024;
  int isV = idx >= 256;
  if (isV) idx -= 256;
  int kvg = idx & 3;
  long rb = (long)(idx >> 2) * 64;
  int row = t >> 2, c = (t & 3) * 32;
  int b = (int)(rb >> 11);
  int c8 = b * 4 + kvg;
  long nloc = rb & 2047;
  if (!isV) {
    const u16* src = &qkv[(rb + row) * 3072 + 2048 + kvg * 128 + c];
    float x[32];
    for (int i = 0; i < 4; i++) {
      uint4 v = *(const uint4*)&src[i * 8];
      unsigned vv[4] = {v.x, v.y, v.z, v.w};
      for (int jj = 0; jj < 4; jj++) {
        x[i * 8 + jj * 2] = b2f((u16)(vv[jj] & 0xffff));
        x[i * 8 + jj * 2 + 1] = b2f((u16)(vv[jj] >> 16));
      }
    }
    float bt[32];
    for (int i = 0; i < 32; i++) bt[i] = exp2f(logsig(x[i]) * 0.0901684411f);
    float mx = x[0];
    for (int i = 1; i < 32; i++) mx = fmaxf(mx, x[i]);
    mx = fmaxf(mx, __shfl_xor(mx, 1));
    mx = fmaxf(mx, __shfl_xor(mx, 2));
    float sm = 0.f;
    for (int i = 0; i < 32; i++) { x[i] = exp2f((x[i] - mx) * L2E); sm += x[i]; }
    sm += __shfl_xor(sm, 1);
    sm += __shfl_xor(sm, 2);
    float inv = 1.f / sm;
    unsigned pks[16], pkb[16];
    for (int i = 0; i < 16; i++) {
      float s0 = x[2 * i] * inv, s1 = x[2 * i + 1] * inv;
      pks[i] = packbf(s0, s1);
      pkb[i] = packbf(s0 * bt[2 * i], s1 * bt[2 * i + 1]);
    }
    u16* d1 = &ksb[(rb + row) * 512 + kvg * 128 + c];
    u16* d2 = &kbb[(rb + row) * 512 + kvg * 128 + c];
    for (int i = 0; i < 4; i++) {
      *(uint4*)&d1[i * 8] = *(const uint4*)&pks[i * 4];
      *(uint4*)&d2[i * 8] = *(const uint4*)&pkb[i * 4];
    }
    for (int i = 0; i < 16; i++) {
      T[c + 2 * i][row] = (u16)(pkb[i] & 0xffff);
      T[c + 2 * i + 1][row] = (u16)(pkb[i] >> 16);
    }
  } else {
    const u16* src = &qkv[(rb + row) * 3072 + 2560 + kvg * 128 + c];
    for (int i = 0; i < 4; i++) {
      uint4 v = *(const uint4*)&src[i * 8];
      unsigned vv[4] = {v.x, v.y, v.z, v.w};
      for (int jj = 0; jj < 4; jj++) {
        T[c + i * 8 + jj * 2][row] = (u16)(vv[jj] & 0xffff);
        T[c + i * 8 + jj * 2 + 1][row] = (u16)(vv[jj] >> 16);
      }
    }
  }
  __syncthreads();
  int dr = t >> 1, nc = (t & 1) * 32;
  u16* dst = isV ? vTb : kbT;
  u16* dp = &dst[((long)(c8 * 128 + dr)) * 2048 + nloc + nc];
  for (int i = 0; i < 4; i++)
    *(uint4*)&dp[i * 8] = *(const uint4*)&T[dr][nc + i * 8];
}

// ---------------- delta-rule phase 1 ----------------
__global__ __launch_bounds__(256) void k_phase1(const u16* __restrict__ ksb,
    const u16* __restrict__ kbb, const u16* __restrict__ kbT,
    const u16* __restrict__ qkv, u16* __restrict__ W_g, u16* __restrict__ U0_g,
    u16* __restrict__ M_g, float* __restrict__ NTT_g) {
  __shared__ u16 Pm[64][72];
  __shared__ u16 PT[64][72];
  __shared__ u16 slab[4][64][72];
  int cc = blockIdx.x;
  int c8 = cc >> 5, j = cc & 31;
  int b = c8 >> 2, kv = c8 & 3;
  long rb = (long)b * 2048 + j * 64;
  int w = threadIdx.x >> 6, ln = threadIdx.x & 63, l15 = ln & 15, q = ln >> 4;
  {
    f32x4 a4[4] = {};
    int m0 = w * 16;
    for (int ks = 0; ks < 4; ks++) {
      bf16x8 af = *(const bf16x8*)&ksb[(rb + m0 + l15) * 512 + kv * 128 + ks * 32 + q * 8];
      for (int nt = 0; nt < 4; nt++) {
        bf16x8 bfr = *(const bf16x8*)&kbb[(rb + nt * 16 + l15) * 512 + kv * 128 + ks * 32 + q * 8];
        a4[nt] = mfma(af, bfr, a4[nt]);
      }
    }
    for (int nt = 0; nt < 4; nt++)
      for (int r = 0; r < 4; r++) {
        int m = m0 + q * 4 + r, n = nt * 16 + l15;
        u16 h = f2b((m > n) ? -a4[nt][r] : 0.f);
        Pm[m][n] = h; PT[n][m] = h;
      }
  }
  for (int idx = threadIdx.x; idx < 16384; idx += 256) {
    int s = idx >> 12, rem = idx & 4095, t = rem >> 6, c = rem & 63;
    u16 v;
    if (s < 2) v = ksb[(rb + t) * 512 + kv * 128 + s * 64 + c];
    else       v = qkv[(rb + t) * 3072 + 2560 + kv * 128 + (s - 2) * 64 + c];
    slab[s][c][t] = v;
  }
  __syncthreads();
  f32x4 X[4][4];
  for (int mt = 0; mt < 4; mt++)
    for (int nt = 0; nt < 4; nt++)
      for (int r = 0; r < 4; r++)
        X[mt][nt][r] = b2f(slab[w][nt * 16 + l15][mt * 16 + q * 4 + r]);
  for (int f = 0; f < 6; f++) {
    for (int ks = 0; ks < 2; ks++) {
      bf16x8 af[4], bfr[4];
      for (int mt = 0; mt < 4; mt++)
        af[mt] = *(const bf16x8*)&Pm[mt * 16 + l15][ks * 32 + q * 8];
      for (int nt = 0; nt < 4; nt++)
        bfr[nt] = *(const bf16x8*)&slab[w][nt * 16 + l15][ks * 32 + q * 8];
      for (int mt = 0; mt < 4; mt++)
        for (int nt = 0; nt < 4; nt++)
          X[mt][nt] = mfma(af[mt], bfr[nt], X[mt][nt]);
    }
    f32x4 pn[4] = {};
    if (f < 5) {
      int m0 = w * 16;
      for (int ks = 0; ks < 2; ks++) {
        bf16x8 af = *(const bf16x8*)&Pm[m0 + l15][ks * 32 + q * 8];
        for (int nt = 0; nt < 4; nt++) {
          bf16x8 bfr = *(const bf16x8*)&PT[nt * 16 + l15][ks * 32 + q * 8];
          pn[nt] = mfma(af, bfr, pn[nt]);
        }
      }
    }
    __syncthreads();
    for (int mt = 0; mt < 4; mt++)
      for (int nt = 0; nt < 4; nt++)
        for (int r = 0; r < 4; r++)
          slab[w][nt * 16 + l15][mt * 16 + q * 4 + r] = f2b(X[mt][nt][r]);
    if (f < 5) {
      int m0 = w * 16;
      for (int nt = 0; nt < 4; nt++)
        for (int r = 0; r < 4; r++) {
          int m = m0 + q * 4 + r, n = nt * 16 + l15;
          u16 h = f2b(pn[nt][r]);
          Pm[m][n] = h; PT[n][m] = h;
        }
    }
    __syncthreads();
  }
  for (int idx = threadIdx.x; idx < 8192; idx += 256) {
    int t = idx >> 7, d = idx & 127;
    W_g[(long)cc * 8192 + idx] = slab[d >> 6][d & 63][t];
  }
  for (int idx = threadIdx.x; idx < 8192; idx += 256) {
    int t = idx >> 7, e = idx & 127;
    U0_g[(long)cc * 8192 + idx] = slab[2 + (e >> 6)][e & 63][t];
  }
  {
    f32x4 acc[2][8] = {};
    int m0 = w * 32;
    for (int ks = 0; ks < 2; ks++) {
      bf16x8 af[2], bfr[8];
      for (int mt = 0; mt < 2; mt++)
        af[mt] = *(const bf16x8*)&kbT[((long)(c8 * 128 + m0 + mt * 16 + l15)) * 2048 + j * 64 + ks * 32 + q * 8];
      for (int nt = 0; nt < 8; nt++) {
        int n = nt * 16 + l15;
        bfr[nt] = *(const bf16x8*)&slab[n >> 6][n & 63][ks * 32 + q * 8];
      }
      for (int mt = 0; mt < 2; mt++)
        for (int nt = 0; nt < 8; nt++)
          acc[mt][nt] = mfma(af[mt], bfr[nt], acc[mt][nt]);
    }
    for (int mt = 0; mt < 2; mt++)
      for (int nt = 0; nt < 8; nt++)
        for (int r = 0; r < 4; r++) {
          int i_ = m0 + mt * 16 + q * 4 + r, jj = nt * 16 + l15;
          M_g[(long)cc * 16384 + (long)i_ * 128 + jj] =
              f2b(((i_ == jj) ? 1.f : 0.f) - acc[mt][nt][r]);
        }
  }
  {
    f32x4 acc[2][8] = {};
    int m0 = w * 32;
    for (int ks = 0; ks < 2; ks++) {
      bf16x8 af[2], bfr[8];
      for (int mt = 0; mt < 2; mt++)
        af[mt] = *(const bf16x8*)&kbT[((long)(c8 * 128 + m0 + mt * 16 + l15)) * 2048 + j * 64 + ks * 32 + q * 8];
      for (int nt = 0; nt < 8; nt++) {
        int e = nt * 16 + l15;
        bfr[nt] = *(const bf16x8*)&slab[2 + (e >> 6)][e & 63][ks * 32 + q * 8];
      }
      for (int mt = 0; mt < 2; mt++)
        for (int nt = 0; nt < 8; nt++)
          acc[mt][nt] = mfma(af[mt], bfr[nt], acc[mt][nt]);
    }
    for (int mt = 0; mt < 2; mt++)
      for (int nt = 0; nt < 8; nt++)
        for (int r = 0; r < 4; r++) {
          int i_ = m0 + mt * 16 + q * 4 + r, e = nt * 16 + l15;
          NTT_g[(long)cc * 16384 + (long)i_ * 128 + e] = acc[mt][nt][r];
        }
  }
}

// ---------------- phase 2: sequential chunk scan, prefetched ----------------
struct P2Buf { bf16x8 W[4]; bf16x8 M[4][2]; f32x4 NT[2]; ushort4 U0; };

__global__ __launch_bounds__(256) void k_phase2(const u16* __restrict__ W_g,
    const u16* __restrict__ U0_g, const u16* __restrict__ M_g,
    const float* __restrict__ NTT_g, u16* __restrict__ St0_g,
    u16* __restrict__ UT_g) {
  __shared__ u16 St[16][136];
  int c8 = blockIdx.x & 7, eb = blockIdx.x >> 3;
  int e0 = eb * 16;
  int w = threadIdx.x >> 6, ln = threadIdx.x & 63, l15 = ln & 15, q = ln >> 4;
  for (int idx = threadIdx.x; idx < 16 * 128; idx += 256)
    St[idx >> 7][idx & 127] = 0;
  __syncthreads();

  auto loadbuf = [&](P2Buf& B, long cc) {
    for (int ks = 0; ks < 4; ks++)
      B.W[ks] = *(const bf16x8*)&W_g[cc * 8192 + (long)(w * 16 + l15) * 128 + ks * 32 + q * 8];
    for (int ks = 0; ks < 4; ks++)
      for (int nt = 0; nt < 2; nt++)
        B.M[ks][nt] = *(const bf16x8*)&M_g[cc * 16384 + (long)(w * 32 + nt * 16 + l15) * 128 + ks * 32 + q * 8];
    for (int nt = 0; nt < 2; nt++)
      B.NT[nt] = *(const f32x4*)&NTT_g[cc * 16384 + (long)(w * 32 + nt * 16 + l15) * 128 + e0 + q * 4];
    B.U0 = *(const ushort4*)&U0_g[cc * 8192 + (long)(w * 16 + l15) * 128 + e0 + q * 4];
  };

  auto step = [&](long cc, P2Buf& cur, P2Buf& nxt, bool pf) {
    if (pf) loadbuf(nxt, cc + 1);
    for (int idx = threadIdx.x; idx < 2048; idx += 256)
      St0_g[cc * 16384 + (long)(e0 + (idx >> 7)) * 128 + (idx & 127)] = St[idx >> 7][idx & 127];
    bf16x8 sf[4];
    for (int ks = 0; ks < 4; ks++)
      sf[ks] = *(const bf16x8*)&St[l15][ks * 32 + q * 8];
    f32x4 acc = {};
    for (int ks = 0; ks < 4; ks++) acc = mfma(sf[ks], cur.W[ks], acc);
    const u16* u0p = (const u16*)&cur.U0;
    for (int r = 0; r < 4; r++)
      UT_g[cc * 8192 + (long)(e0 + q * 4 + r) * 64 + w * 16 + l15] = f2b(b2f(u0p[r]) - acc[r]);
    f32x4 acc2[2] = {cur.NT[0], cur.NT[1]};
    for (int ks = 0; ks < 4; ks++)
      for (int nt = 0; nt < 2; nt++)
        acc2[nt] = mfma(sf[ks], cur.M[ks][nt], acc2[nt]);
    __syncthreads();
    for (int nt = 0; nt < 2; nt++)
      for (int r = 0; r < 4; r++)
        St[q * 4 + r][w * 32 + nt * 16 + l15] = f2b(acc2[nt][r]);
    __syncthreads();
  };

  P2Buf A, B;
  long base = (long)c8 * 32;
  loadbuf(A, base);
  for (int j = 0; j < 32; j += 2) {
    step(base + j, A, B, true);
    step(base + j + 1, B, A, j + 2 < 32);
  }
}

// ---------------- phase 3 ----------------
__global__ __launch_bounds__(256) void k_phase3(const u16* __restrict__ qsb,
    const u16* __restrict__ kbb, const u16* __restrict__ St0_g,
    const u16* __restrict__ UT_g, u16* __restrict__ o_lin) {
  __shared__ u16 Pl[64][72];
  int cc = blockIdx.x >> 2, hh = blockIdx.x & 3;
  int c8 = cc >> 5, j = cc & 31;
  int b = c8 >> 2, kv = c8 & 3, hq = kv * 4 + hh;
  long rb = (long)b * 2048 + j * 64;
  int w = threadIdx.x >> 6, ln = threadIdx.x & 63, l15 = ln & 15, q = ln >> 4;
  int m0 = w * 16;
  f32x4 O[8] = {};
  for (int ks = 0; ks < 4; ks++) {
    bf16x8 af = *(const bf16x8*)&qsb[(rb + m0 + l15) * 2048 + hq * 128 + ks * 32 + q * 8];
    for (int nt = 0; nt < 8; nt++) {
      bf16x8 bfr = *(const bf16x8*)&St0_g[(long)cc * 16384 + (long)(nt * 16 + l15) * 128 + ks * 32 + q * 8];
      O[nt] = mfma(af, bfr, O[nt]);
    }
  }
  {
    f32x4 p4[4] = {};
    for (int ks = 0; ks < 4; ks++) {
      bf16x8 af = *(const bf16x8*)&qsb[(rb + m0 + l15) * 2048 + hq * 128 + ks * 32 + q * 8];
      for (int nt = 0; nt < 4; nt++) {
        bf16x8 bfr = *(const bf16x8*)&kbb[(rb + nt * 16 + l15) * 512 + kv * 128 + ks * 32 + q * 8];
        p4[nt] = mfma(af, bfr, p4[nt]);
      }
    }
    for (int nt = 0; nt < 4; nt++)
      for (int r = 0; r < 4; r++) {
        int m = m0 + q * 4 + r, n = nt * 16 + l15;
        Pl[m][n] = f2b((m >= n) ? p4[nt][r] : 0.f);
      }
  }
  __syncthreads();
  for (int ks = 0; ks < 2; ks++) {
    bf16x8 af = *(const bf16x8*)&Pl[m0 + l15][ks * 32 + q * 8];
    for (int nt = 0; nt < 8; nt++) {
      bf16x8 bfr = *(const bf16x8*)&UT_g[(long)cc * 8192 + (long)(nt * 16 + l15) * 64 + ks * 32 + q * 8];
      O[nt] = mfma(af, bfr, O[nt]);
    }
  }
  for (int nt = 0; nt < 8; nt++)
    for (int r = 0; r < 4; r++) {
      int m = m0 + q * 4 + r, e = nt * 16 + l15;
      o_lin[(rb + m) * 2048 + hq * 128 + e] = f2b(O[nt][r]);
    }
}

// ---------------- flash: GEMM-style, 128-q tiles, XOR-swizzled LDS K/V ------
// Block = (b, h, pair{p, 15-p}): 256 blocks, 17 KV-tile units each, 1/CU.
// K dbuf + V in LDS via global_load_lds with XOR-swizzled source columns:
// LDS row r, block position p (8 u16) holds global d-block p ^ (r & 15)
// -> fragment reads spread across banks (2-way, free) instead of 16-way.
__global__ __launch_bounds__(256, 1) void k_flash(const u16* __restrict__ qkv,
    const u16* __restrict__ vTb, const u16* __restrict__ o_lin,
    u16* __restrict__ o_comb) {
  __shared__ u16 Ks[2][16384];   // [buf][k-row][d swizzled]
  __shared__ u16 Vs[16384];      // [e][n-local swizzled]
  __shared__ u16 P[4][32][136];  // [wave][q-local][k]
  int pr = blockIdx.x & 7, h = (blockIdx.x >> 3) & 15, b = blockIdx.x >> 7;
  int kv = h >> 2;
  int t = threadIdx.x;
  int w = t >> 6, ln = t & 63, l15 = ln & 15, qd = ln >> 4;
  const float sc2 = 0.127517444f;  // (1/sqrt(128)) * log2(e)
  long kvb = (long)b * 2048;
  const u16* Kgb = &qkv[(kvb) * 3072 + 2048 + kv * 128];
  const u16* Vgb = &vTb[(long)(b * 4 + kv) * 128 * 2048];
  // staging: thread t covers row srow, source col-block (t&15)^(srow&15)
  int srow = t >> 4, scol = (((t & 15) ^ (srow & 15)) * 8);
  u16 (*Pw)[136] = P[w];

  for (int sel = 0; sel < 2; sel++) {
    int qt = sel ? 15 - pr : pr;
    long qb = kvb + qt * 128;
    int njt = qt + 1;
    bf16x8 bq[2][4];
    for (int nt = 0; nt < 2; nt++)
      for (int ks = 0; ks < 4; ks++)
        bq[nt][ks] = *(const bf16x8*)&qkv[(qb + w * 32 + nt * 16 + l15) * 3072 + h * 128 + ks * 32 + qd * 8];
    __syncthreads();  // Ks[0] free (prev sel done)
    for (int i = 0; i < 8; i++)
      gll16(Kgb + (long)(i * 16 + srow) * 3072 + scol, &Ks[0][i * 2048 + t * 8]);
    f32x4 O[2][8] = {};
    float psum[2] = {0.f, 0.f};
    for (int jt = 0; jt < njt; jt++) {
      __syncthreads();  // K(jt) staged; Vs free; Ks[(jt+1)&1] free
      for (int i = 0; i < 8; i++)
        gll16(Vgb + (long)(i * 16 + srow) * 2048 + jt * 128 + scol, &Vs[i * 2048 + t * 8]);
      if (jt + 1 < njt) {
        const u16* Kg = Kgb + (long)(jt + 1) * 128 * 3072;
        u16* Kd = &Ks[(jt + 1) & 1][0];
        for (int i = 0; i < 8; i++)
          gll16(Kg + (long)(i * 16 + srow) * 3072 + scol, &Kd[i * 2048 + t * 8]);
      }
      // S^T = K(jt) · Q^T; K frag row mt*16+l15, block (ks*4+qd)^l15
      const u16* Kc = &Ks[jt & 1][0];
      f32x4 st[8][2] = {};
      for (int ks = 0; ks < 4; ks++) {
        int blk = ((ks * 4 + qd) ^ l15) * 8;
        for (int mt = 0; mt < 8; mt++) {
          bf16x8 ak = *(const bf16x8*)&Kc[(mt * 16 + l15) * 128 + blk];
          st[mt][0] = mfma(ak, bq[0][ks], st[mt][0]);
          st[mt][1] = mfma(ak, bq[1][ks], st[mt][1]);
        }
      }
      bool last = (jt == njt - 1);
      for (int nt = 0; nt < 2; nt++) {
        int rg = qt * 128 + w * 32 + nt * 16 + l15;
        for (int mt = 0; mt < 8; mt++) {
          f32x4 v = st[mt][nt];
          float pv[4];
          for (int r = 0; r < 4; r++) {
            float p = exp2f(v[r] * sc2);
            int kg = jt * 128 + mt * 16 + qd * 4 + r;
            if (last && kg > rg) p = 0.f;
            pv[r] = p;
            psum[nt] += p;
          }
          unsigned pu[2] = {packbf(pv[0], pv[1]), packbf(pv[2], pv[3])};
          *(uint2*)&Pw[nt * 16 + l15][mt * 16 + qd * 4] = *(const uint2*)pu;
        }
      }
      __syncthreads();  // drains V(jt) (+K(jt+1)); vmcnt covered by QK above
      // O += P · V; V frag row et*16+l15, block (ks*4+qd)^l15
      bf16x8 ap[2][4];
      for (int mt2 = 0; mt2 < 2; mt2++)
        for (int ks = 0; ks < 4; ks++)
          ap[mt2][ks] = *(const bf16x8*)&Pw[mt2 * 16 + l15][ks * 32 + qd * 8];
      for (int ks = 0; ks < 4; ks++) {
        int blk = ((ks * 4 + qd) ^ l15) * 8;
        for (int et = 0; et < 8; et++) {
          bf16x8 bv = *(const bf16x8*)&Vs[(et * 16 + l15) * 128 + blk];
          O[0][et] = mfma(ap[0][ks], bv, O[0][et]);
          O[1][et] = mfma(ap[1][ks], bv, O[1][et]);
        }
      }
    }
    for (int nt = 0; nt < 2; nt++) {
      psum[nt] += __shfl_xor(psum[nt], 16);
      psum[nt] += __shfl_xor(psum[nt], 32);
    }
    for (int mt2 = 0; mt2 < 2; mt2++)
      for (int r = 0; r < 4; r++) {
        float linv = 1.f / __shfl(psum[mt2], qd * 4 + r);
        int rowg = w * 32 + mt2 * 16 + qd * 4 + r;
        for (int et = 0; et < 8; et++) {
          long off = (qb + rowg) * 2048 + h * 128 + et * 16 + l15;
          o_comb[off] = f2b(0.5f * O[mt2][et][r] * linv + 0.5f * b2f(o_lin[off]));
        }
      }
  }
}

// ---------------- launch ----------------
extern "C" void kernel_launch(void* const* d_in, const int* in_sizes, int n_in,
                              void* d_out, int out_size, void* d_ws, size_t ws_size,
                              hipStream_t stream) {
  const float* hs = (const float*)d_in[0];
  const float* wq = (const float*)d_in[1];
  const float* wk = (const float*)d_in[2];
  const float* wv = (const float*)d_in[3];
  const float* wo = (const float*)d_in[4];

  char* p = (char*)d_ws;
  auto alloc = [&](size_t bytes) {
    char* r = p;
    p += (bytes + 255) & ~(size_t)255;
    return r;
  };
  u16* hsb    = (u16*)alloc(16777216);   // reused as o_comb
  u16* wqkvT  = (u16*)alloc(12582912);
  u16* woT    = (u16*)alloc(8388608);
  u16* qkv    = (u16*)alloc(25165824);
  u16* qsb    = (u16*)alloc(16777216);
  u16* ksb    = (u16*)alloc(4194304);
  u16* kbb    = (u16*)alloc(4194304);
  u16* kbT    = (u16*)alloc(4194304);
  u16* vTb    = (u16*)alloc(4194304);
  u16* o_lin  = (u16*)alloc(16777216);
  u16* W_g    = (u16*)alloc(4194304);
  u16* U0_g   = (u16*)alloc(4194304);
  u16* M_g    = (u16*)alloc(8388608);
  float* NTT_g = (float*)alloc(16777216);
  u16* St0_g  = (u16*)alloc(8388608);
  u16* UT_g   = (u16*)alloc(4194304);

  k_prep0<<<4608, 256, 0, stream>>>(hs, wq, wk, wv, wo, hsb, wqkvT, woT);
  k_gemm<0><<<dim3(24, 32), 256, 0, stream>>>(hsb, wqkvT, qkv, 4096, 3072, 2048);
  k_act<<<1536, 256, 0, stream>>>(qkv, qsb, ksb, kbb, kbT, vTb);
  k_phase1<<<256, 256, 0, stream>>>(ksb, kbb, kbT, qkv, W_g, U0_g, M_g, NTT_g);
  k_phase2<<<64, 256, 0, stream>>>(W_g, U0_g, M_g, NTT_g, St0_g, UT_g);
  k_phase3<<<1024, 256, 0, stream>>>(qsb, kbb, St0_g, UT_g, o_lin);
  k_flash<<<256, 256, 0, stream>>>(qkv, vTb, o_lin, hsb);
  k_gemm<1><<<dim3(16, 32), 256, 0, stream>>>(hsb, woT, (float*)d_out, 4096, 2048, 2048);
}